// Round 3
// baseline (3187.518 us; speedup 1.0000x reference)
//
#include <hip/hip_runtime.h>
#include <math.h>

#define N_NODES 100000
#define N_EDGES 3200000
#define DIM_IN  128
#define DIM_HID 64
#define DIM_OUT 40

#define BSHIFT 6
#define BNODES 64                                   // nodes per bucket
#define NBUCK ((N_NODES + BNODES - 1) / BNODES)     // 1563

// ---------------- bucket histogram (1563 L2-resident counters) --------------
__global__ __launch_bounds__(256) void hist_kernel(
    const int* __restrict__ dst, int* __restrict__ hist) {
  const int e = blockIdx.x * 256 + threadIdx.x;
  if (e < N_EDGES) atomicAdd(&hist[dst[e] >> BSHIFT], 1);
}

// ---------------- single-block exclusive scan of 1563 bucket counts ---------
__global__ __launch_bounds__(256) void scanb_kernel(
    const int* __restrict__ hist, int* __restrict__ base,
    int* __restrict__ cursor) {
  const int t = threadIdx.x;
  int v[7]; int s = 0;
#pragma unroll
  for (int j = 0; j < 7; ++j) {
    const int i = t * 7 + j;
    v[j] = (i < NBUCK) ? hist[i] : 0;
    s += v[j];
  }
  const int lane = t & 63, wid = t >> 6;
  int incl = s;
#pragma unroll
  for (int off = 1; off < 64; off <<= 1) {
    int n = __shfl_up(incl, off);
    if (lane >= off) incl += n;
  }
  __shared__ int wsum[4];
  if (lane == 63) wsum[wid] = incl;
  __syncthreads();
  int woff = 0;
  for (int k = 0; k < wid; ++k) woff += wsum[k];
  int run = woff + incl - s;   // exclusive prefix for this thread's first item
#pragma unroll
  for (int j = 0; j < 7; ++j) {
    const int i = t * 7 + j;
    if (i < NBUCK) { base[i] = run; cursor[i] = run; }
    run += v[j];
  }
  if (t == 255) base[NBUCK] = N_EDGES;
}

// ---------------- bucket scatter: packed entry = (dstLow<<20)|src, w --------
__global__ __launch_bounds__(256) void scatter_kernel(
    const int* __restrict__ dst, const int* __restrict__ src,
    const float* __restrict__ ew, int* __restrict__ cursor,
    int2* __restrict__ packed) {
  const int e = blockIdx.x * 256 + threadIdx.x;
  if (e >= N_EDGES) return;
  const int t = dst[e];
  const int pos = atomicAdd(&cursor[t >> BSHIFT], 1);
  int2 p;
  p.x = ((t & (BNODES - 1)) << 20) | src[e];   // src < 2^20
  p.y = __float_as_int(ew[e]);
  packed[pos] = p;
}

// ---------------- GEMM1: h = x @ W1   [N,128] x [128,64] -> [N,64] ----------
__global__ __launch_bounds__(256) void gemm1_kernel(
    const float* __restrict__ x, const float* __restrict__ W1,
    float* __restrict__ h) {
  __shared__ float w[DIM_IN * DIM_HID];
  for (int i = threadIdx.x; i < DIM_IN * DIM_HID; i += 256) w[i] = W1[i];
  __syncthreads();
  const int row = blockIdx.x * 4 + (threadIdx.x >> 6);
  const int col = threadIdx.x & 63;
  if (row >= N_NODES) return;
  const float* xr = x + (size_t)row * DIM_IN;
  float acc = 0.f;
#pragma unroll 8
  for (int k = 0; k < DIM_IN; ++k) acc = fmaf(xr[k], w[k * DIM_HID + col], acc);
  h[(size_t)row * DIM_HID + col] = acc;
}

// ------- SPMM1 (bucketed, LDS accumulate) + fused GEMM2 ---------------------
// One WG (4 waves) per bucket of 64 nodes. acc[64x64] in LDS via ds_add_f32;
// epilogue computes h2 = relu(acc) @ W2 directly from LDS.
__global__ __launch_bounds__(256) void spmm64_gemm2_kernel(
    const int* __restrict__ base, const int2* __restrict__ packed,
    const float* __restrict__ h, const float* __restrict__ W2,
    float* __restrict__ h2) {
  __shared__ float acc[BNODES * DIM_HID];   // 16 KB
  __shared__ float w2[DIM_HID * DIM_OUT];   // 10 KB
  const int tid = threadIdx.x;
  const int lane = tid & 63, wid = tid >> 6;
  const int b = blockIdx.x;
  for (int i = tid; i < BNODES * DIM_HID; i += 256) acc[i] = 0.f;
  for (int i = tid; i < DIM_HID * DIM_OUT; i += 256) w2[i] = W2[i];
  const int e0 = base[b], e1 = base[b + 1];
  __syncthreads();

  int e = e0 + wid;
  for (; e + 12 < e1; e += 16) {
    const int2 p0 = packed[e], p1 = packed[e + 4];
    const int2 p2 = packed[e + 8], p3 = packed[e + 12];
    const float a0 = h[(size_t)(p0.x & 0xFFFFF) * DIM_HID + lane];
    const float a1 = h[(size_t)(p1.x & 0xFFFFF) * DIM_HID + lane];
    const float a2 = h[(size_t)(p2.x & 0xFFFFF) * DIM_HID + lane];
    const float a3 = h[(size_t)(p3.x & 0xFFFFF) * DIM_HID + lane];
    atomicAdd(&acc[((p0.x >> 20) & 63) * DIM_HID + lane], __int_as_float(p0.y) * a0);
    atomicAdd(&acc[((p1.x >> 20) & 63) * DIM_HID + lane], __int_as_float(p1.y) * a1);
    atomicAdd(&acc[((p2.x >> 20) & 63) * DIM_HID + lane], __int_as_float(p2.y) * a2);
    atomicAdd(&acc[((p3.x >> 20) & 63) * DIM_HID + lane], __int_as_float(p3.y) * a3);
  }
  for (; e < e1; e += 4) {
    const int2 p = packed[e];
    const float a = h[(size_t)(p.x & 0xFFFFF) * DIM_HID + lane];
    atomicAdd(&acc[((p.x >> 20) & 63) * DIM_HID + lane], __int_as_float(p.y) * a);
  }
  __syncthreads();

  // h2 = relu(acc) @ W2 for this bucket's nodes
  const int nbase = b << BSHIFT;
  const int nodes = min(BNODES, N_NODES - nbase);
  for (int i = tid; i < nodes * DIM_OUT; i += 256) {
    const int n = i / DIM_OUT, c = i - n * DIM_OUT;
    float s = 0.f;
#pragma unroll 16
    for (int k = 0; k < DIM_HID; ++k)
      s = fmaf(fmaxf(acc[n * DIM_HID + k], 0.f), w2[k * DIM_OUT + c], s);
    h2[(size_t)(nbase + n) * DIM_OUT + c] = s;
  }
}

// ------- SPMM2 (bucketed, LDS accumulate) + fused log_softmax ---------------
__global__ __launch_bounds__(256) void spmm40_lsm_kernel(
    const int* __restrict__ base, const int2* __restrict__ packed,
    const float* __restrict__ h2, float* __restrict__ out) {
  __shared__ float acc[BNODES * DIM_OUT];   // 10 KB
  const int tid = threadIdx.x;
  const int lane = tid & 63, wid = tid >> 6;
  const int b = blockIdx.x;
  for (int i = tid; i < BNODES * DIM_OUT; i += 256) acc[i] = 0.f;
  const int e0 = base[b], e1 = base[b + 1];
  __syncthreads();

  const bool act = lane < DIM_OUT;
  int e = e0 + wid;
  for (; e + 12 < e1; e += 16) {
    const int2 p0 = packed[e], p1 = packed[e + 4];
    const int2 p2 = packed[e + 8], p3 = packed[e + 12];
    if (act) {
      const float a0 = h2[(size_t)(p0.x & 0xFFFFF) * DIM_OUT + lane];
      const float a1 = h2[(size_t)(p1.x & 0xFFFFF) * DIM_OUT + lane];
      const float a2 = h2[(size_t)(p2.x & 0xFFFFF) * DIM_OUT + lane];
      const float a3 = h2[(size_t)(p3.x & 0xFFFFF) * DIM_OUT + lane];
      atomicAdd(&acc[((p0.x >> 20) & 63) * DIM_OUT + lane], __int_as_float(p0.y) * a0);
      atomicAdd(&acc[((p1.x >> 20) & 63) * DIM_OUT + lane], __int_as_float(p1.y) * a1);
      atomicAdd(&acc[((p2.x >> 20) & 63) * DIM_OUT + lane], __int_as_float(p2.y) * a2);
      atomicAdd(&acc[((p3.x >> 20) & 63) * DIM_OUT + lane], __int_as_float(p3.y) * a3);
    }
  }
  for (; e < e1; e += 4) {
    const int2 p = packed[e];
    if (act) {
      const float a = h2[(size_t)(p.x & 0xFFFFF) * DIM_OUT + lane];
      atomicAdd(&acc[((p.x >> 20) & 63) * DIM_OUT + lane], __int_as_float(p.y) * a);
    }
  }
  __syncthreads();

  // log_softmax per node (wave handles nodes wid, wid+4, ...)
  const int nbase = b << BSHIFT;
  const int nodes = min(BNODES, N_NODES - nbase);
  for (int n = wid; n < nodes; n += 4) {
    const float v = act ? acc[n * DIM_OUT + lane] : -INFINITY;
    float m = v;
#pragma unroll
    for (int off = 32; off > 0; off >>= 1) m = fmaxf(m, __shfl_xor(m, off));
    const float ex = act ? expf(v - m) : 0.f;
    float s = ex;
#pragma unroll
    for (int off = 32; off > 0; off >>= 1) s += __shfl_xor(s, off);
    const float ls = logf(s);
    if (act) out[(size_t)(nbase + n) * DIM_OUT + lane] = v - m - ls;
  }
}

extern "C" void kernel_launch(void* const* d_in, const int* in_sizes, int n_in,
                              void* d_out, int out_size, void* d_ws, size_t ws_size,
                              hipStream_t stream) {
  const float* x  = (const float*)d_in[0];
  const int*   ei = (const int*)d_in[1];   // [2, E]: first E = dst, next E = src
  const float* ew = (const float*)d_in[2];
  const float* W1 = (const float*)d_in[3];
  const float* W2 = (const float*)d_in[4];
  float* out = (float*)d_out;

  const int* dst = ei;
  const int* src = ei + N_EDGES;

  // --------- workspace layout ---------
  char* p = (char*)d_ws;
  int2*  packed = (int2*)p;   p += (size_t)N_EDGES * 8;               // 25.6 MB
  float* bufA   = (float*)p;  p += (size_t)N_NODES * DIM_HID * 4;     // 25.6 MB (h)
  float* bufB   = (float*)p;  p += (size_t)N_NODES * DIM_OUT * 4;     // 16 MB  (h2)
  int*   hist   = (int*)p;    p += (size_t)NBUCK * 4;
  int*   base   = (int*)p;    p += (size_t)(NBUCK + 8) * 4;
  int*   cursor = (int*)p;    p += (size_t)NBUCK * 4;

  const int egrid = (N_EDGES + 255) / 256;          // 12500
  const int ngrid4 = (N_NODES + 3) / 4;             // 25000

  // --------- bucket build ---------
  hipMemsetAsync(hist, 0, (size_t)NBUCK * 4, stream);
  hist_kernel<<<egrid, 256, 0, stream>>>(dst, hist);
  scanb_kernel<<<1, 256, 0, stream>>>(hist, base, cursor);
  scatter_kernel<<<egrid, 256, 0, stream>>>(dst, src, ew, cursor, packed);

  // --------- layer 1 (+ fused GEMM2) ---------
  gemm1_kernel<<<ngrid4, 256, 0, stream>>>(x, W1, bufA);
  spmm64_gemm2_kernel<<<NBUCK, 256, 0, stream>>>(base, packed, bufA, W2, bufB);

  // --------- layer 2 + fused log_softmax ---------
  spmm40_lsm_kernel<<<NBUCK, 256, 0, stream>>>(base, packed, bufB, out);
}

// Round 4
// 732.573 us; speedup vs baseline: 4.3511x; 4.3511x over previous
//
#include <hip/hip_runtime.h>
#include <math.h>

#define N_NODES 100000
#define N_EDGES 3200000
#define DIM_IN  128
#define DIM_HID 64
#define DIM_OUT 40

#define BSHIFT 6
#define BNODES 64
#define NBUCK ((N_NODES + BNODES - 1) / BNODES)   // 1563
#define HPAD  16                                  // counter stride: 16 ints = 64 B (own cache line)
#define CHUNK 4096
#define NCHUNK ((N_EDGES + CHUNK - 1) / CHUNK)    // 782

// ---- hist: per-WG LDS histogram of dst>>6, flushed to padded global counters
__global__ __launch_bounds__(256) void hist_kernel(
    const int* __restrict__ dst, int* __restrict__ hist) {
  __shared__ int cnt[NBUCK];
  const int t = threadIdx.x;
  for (int i = t; i < NBUCK; i += 256) cnt[i] = 0;
  __syncthreads();
  const int e0 = blockIdx.x * CHUNK;
  const int e1 = min(e0 + CHUNK, N_EDGES);
  for (int e = e0 + t; e < e1; e += 256) atomicAdd(&cnt[dst[e] >> BSHIFT], 1);
  __syncthreads();
  for (int i = t; i < NBUCK; i += 256) {
    const int c = cnt[i];
    if (c) atomicAdd(&hist[i * HPAD], c);
  }
}

// ---- exclusive scan of 1563 bucket counts (single block) -------------------
__global__ __launch_bounds__(256) void scanb_kernel(
    const int* __restrict__ hist, int* __restrict__ base,
    int* __restrict__ cursor, int* __restrict__ ptr) {
  const int t = threadIdx.x;
  int v[7]; int s = 0;
#pragma unroll
  for (int j = 0; j < 7; ++j) {
    const int i = t * 7 + j;
    v[j] = (i < NBUCK) ? hist[i * HPAD] : 0;
    s += v[j];
  }
  const int lane = t & 63, wid = t >> 6;
  int incl = s;
#pragma unroll
  for (int off = 1; off < 64; off <<= 1) {
    int n = __shfl_up(incl, off);
    if (lane >= off) incl += n;
  }
  __shared__ int wsum[4];
  if (lane == 63) wsum[wid] = incl;
  __syncthreads();
  int woff = 0;
  for (int k = 0; k < wid; ++k) woff += wsum[k];
  int run = woff + incl - s;
#pragma unroll
  for (int j = 0; j < 7; ++j) {
    const int i = t * 7 + j;
    if (i < NBUCK) { base[i] = run; cursor[i * HPAD] = run; }
    run += v[j];
  }
  if (t == 255) { base[NBUCK] = N_EDGES; ptr[N_NODES] = N_EDGES; }
}

// ---- scatter pass 1: edges -> bucket regions, per-WG LDS reservation -------
__global__ __launch_bounds__(256) void scatter_kernel(
    const int* __restrict__ dst, const int* __restrict__ src,
    const float* __restrict__ ew, int* __restrict__ cursor,
    int2* __restrict__ packed1) {
  __shared__ int cnt[NBUCK];
  const int t = threadIdx.x;
  for (int i = t; i < NBUCK; i += 256) cnt[i] = 0;
  __syncthreads();
  const int e0 = blockIdx.x * CHUNK;
  const int e1 = min(e0 + CHUNK, N_EDGES);
  for (int e = e0 + t; e < e1; e += 256) atomicAdd(&cnt[dst[e] >> BSHIFT], 1);
  __syncthreads();
  for (int i = t; i < NBUCK; i += 256) {
    const int c = cnt[i];
    cnt[i] = c ? atomicAdd(&cursor[i * HPAD], c) : 0;  // cnt becomes global cursor
  }
  __syncthreads();
  for (int e = e0 + t; e < e1; e += 256) {
    const int d = dst[e];
    const int pos = atomicAdd(&cnt[d >> BSHIFT], 1);
    int2 q;
    q.x = ((d & (BNODES - 1)) << 20) | src[e];   // src < 2^20
    q.y = __float_as_int(ew[e]);
    packed1[pos] = q;
  }
}

// ---- sort pass 2: within each bucket, order by node; emit ptr --------------
__global__ __launch_bounds__(256) void sort2_kernel(
    const int* __restrict__ base, const int2* __restrict__ packed1,
    int2* __restrict__ packed2, int* __restrict__ ptr) {
  __shared__ int cnt[BNODES];
  __shared__ int cur[BNODES];
  const int t = threadIdx.x;
  const int b = blockIdx.x;
  if (t < BNODES) cnt[t] = 0;
  const int e0 = base[b], e1 = base[b + 1];
  __syncthreads();
  for (int e = e0 + t; e < e1; e += 256)
    atomicAdd(&cnt[(packed1[e].x >> 20) & (BNODES - 1)], 1);
  __syncthreads();
  if (t < 64) {
    const int v = cnt[t];
    int incl = v;
#pragma unroll
    for (int off = 1; off < 64; off <<= 1) {
      int n = __shfl_up(incl, off);
      if (t >= off) incl += n;
    }
    const int start = e0 + incl - v;
    cur[t] = start;
    const int node = (b << BSHIFT) + t;
    if (node < N_NODES) ptr[node] = start;
  }
  __syncthreads();
  for (int e = e0 + t; e < e1; e += 256) {
    const int2 p = packed1[e];
    const int pos = atomicAdd(&cur[(p.x >> 20) & (BNODES - 1)], 1);
    int2 q; q.x = p.x & 0xFFFFF; q.y = p.y;
    packed2[pos] = q;
  }
}

// ---- GEMM1: h = x @ W1, 16 rows/block to amortize W1 staging ---------------
__global__ __launch_bounds__(256) void gemm1_kernel(
    const float* __restrict__ x, const float* __restrict__ W1,
    float* __restrict__ h) {
  __shared__ float w[DIM_IN * DIM_HID];   // 32 KB
  for (int i = threadIdx.x; i < DIM_IN * DIM_HID; i += 256) w[i] = W1[i];
  __syncthreads();
  const int lane = threadIdx.x & 63, wid = threadIdx.x >> 6;
#pragma unroll
  for (int r = 0; r < 4; ++r) {
    const int row = blockIdx.x * 16 + r * 4 + wid;   // 100000 % 16 == 0
    const float4* xr = (const float4*)(x + (size_t)row * DIM_IN);
    float acc = 0.f;
#pragma unroll 8
    for (int k4 = 0; k4 < DIM_IN / 4; ++k4) {
      const float4 xv = xr[k4];
      acc = fmaf(xv.x, w[(k4 * 4 + 0) * DIM_HID + lane], acc);
      acc = fmaf(xv.y, w[(k4 * 4 + 1) * DIM_HID + lane], acc);
      acc = fmaf(xv.z, w[(k4 * 4 + 2) * DIM_HID + lane], acc);
      acc = fmaf(xv.w, w[(k4 * 4 + 3) * DIM_HID + lane], acc);
    }
    h[(size_t)row * DIM_HID + lane] = acc;
  }
}

// ---- SPMM1 (CSR, wave/node, 8-way MLP) + fused GEMM2 epilogue --------------
__global__ __launch_bounds__(256) void spmm64_g2_kernel(
    const int* __restrict__ ptr, const int2* __restrict__ packed,
    const float* __restrict__ h, const float* __restrict__ W2,
    float* __restrict__ h2) {
  __shared__ float w2[DIM_HID * DIM_OUT];   // 10 KB
  for (int i = threadIdx.x; i < DIM_HID * DIM_OUT; i += 256) w2[i] = W2[i];
  __syncthreads();
  const int node = blockIdx.x * 4 + (threadIdx.x >> 6);   // 25000*4 == N
  const int lane = threadIdx.x & 63;
  int e = ptr[node];
  const int end = ptr[node + 1];
  float acc = 0.f;
  for (; e + 8 <= end; e += 8) {
    const int2 p0 = packed[e],     p1 = packed[e + 1];
    const int2 p2 = packed[e + 2], p3 = packed[e + 3];
    const int2 p4 = packed[e + 4], p5 = packed[e + 5];
    const int2 p6 = packed[e + 6], p7 = packed[e + 7];
    const float a0 = h[(size_t)p0.x * DIM_HID + lane];
    const float a1 = h[(size_t)p1.x * DIM_HID + lane];
    const float a2 = h[(size_t)p2.x * DIM_HID + lane];
    const float a3 = h[(size_t)p3.x * DIM_HID + lane];
    const float a4 = h[(size_t)p4.x * DIM_HID + lane];
    const float a5 = h[(size_t)p5.x * DIM_HID + lane];
    const float a6 = h[(size_t)p6.x * DIM_HID + lane];
    const float a7 = h[(size_t)p7.x * DIM_HID + lane];
    acc = fmaf(__int_as_float(p0.y), a0, acc);
    acc = fmaf(__int_as_float(p1.y), a1, acc);
    acc = fmaf(__int_as_float(p2.y), a2, acc);
    acc = fmaf(__int_as_float(p3.y), a3, acc);
    acc = fmaf(__int_as_float(p4.y), a4, acc);
    acc = fmaf(__int_as_float(p5.y), a5, acc);
    acc = fmaf(__int_as_float(p6.y), a6, acc);
    acc = fmaf(__int_as_float(p7.y), a7, acc);
  }
  for (; e < end; ++e) {
    const int2 p = packed[e];
    acc = fmaf(__int_as_float(p.y), h[(size_t)p.x * DIM_HID + lane], acc);
  }
  // fused GEMM2: h2[node, :] = relu(agg_row) @ W2 via lane broadcast
  const float r = fmaxf(acc, 0.f);
  const int c = (lane < DIM_OUT) ? lane : (DIM_OUT - 1);
  float s = 0.f;
#pragma unroll
  for (int k = 0; k < DIM_HID; ++k)
    s = fmaf(__shfl(r, k), w2[k * DIM_OUT + c], s);
  if (lane < DIM_OUT) h2[(size_t)node * DIM_OUT + lane] = s;
}

// ---- SPMM2 (CSR, wave/node, 8-way MLP) + fused log_softmax -----------------
__global__ __launch_bounds__(256) void spmm40_lsm_kernel(
    const int* __restrict__ ptr, const int2* __restrict__ packed,
    const float* __restrict__ h2, float* __restrict__ out) {
  const int node = blockIdx.x * 4 + (threadIdx.x >> 6);
  const int lane = threadIdx.x & 63;
  const int l = (lane < DIM_OUT) ? lane : (DIM_OUT - 1);
  int e = ptr[node];
  const int end = ptr[node + 1];
  float acc = 0.f;
  for (; e + 8 <= end; e += 8) {
    const int2 p0 = packed[e],     p1 = packed[e + 1];
    const int2 p2 = packed[e + 2], p3 = packed[e + 3];
    const int2 p4 = packed[e + 4], p5 = packed[e + 5];
    const int2 p6 = packed[e + 6], p7 = packed[e + 7];
    const float a0 = h2[(size_t)p0.x * DIM_OUT + l];
    const float a1 = h2[(size_t)p1.x * DIM_OUT + l];
    const float a2 = h2[(size_t)p2.x * DIM_OUT + l];
    const float a3 = h2[(size_t)p3.x * DIM_OUT + l];
    const float a4 = h2[(size_t)p4.x * DIM_OUT + l];
    const float a5 = h2[(size_t)p5.x * DIM_OUT + l];
    const float a6 = h2[(size_t)p6.x * DIM_OUT + l];
    const float a7 = h2[(size_t)p7.x * DIM_OUT + l];
    acc = fmaf(__int_as_float(p0.y), a0, acc);
    acc = fmaf(__int_as_float(p1.y), a1, acc);
    acc = fmaf(__int_as_float(p2.y), a2, acc);
    acc = fmaf(__int_as_float(p3.y), a3, acc);
    acc = fmaf(__int_as_float(p4.y), a4, acc);
    acc = fmaf(__int_as_float(p5.y), a5, acc);
    acc = fmaf(__int_as_float(p6.y), a6, acc);
    acc = fmaf(__int_as_float(p7.y), a7, acc);
  }
  for (; e < end; ++e) {
    const int2 p = packed[e];
    acc = fmaf(__int_as_float(p.y), h2[(size_t)p.x * DIM_OUT + l], acc);
  }
  const bool act = (lane < DIM_OUT);
  const float v = act ? acc : -INFINITY;
  float m = v;
#pragma unroll
  for (int off = 32; off > 0; off >>= 1) m = fmaxf(m, __shfl_xor(m, off));
  const float ex = act ? expf(v - m) : 0.f;
  float s = ex;
#pragma unroll
  for (int off = 32; off > 0; off >>= 1) s += __shfl_xor(s, off);
  const float ls = logf(s);
  if (act) out[(size_t)node * DIM_OUT + lane] = v - m - ls;
}

extern "C" void kernel_launch(void* const* d_in, const int* in_sizes, int n_in,
                              void* d_out, int out_size, void* d_ws, size_t ws_size,
                              hipStream_t stream) {
  const float* x  = (const float*)d_in[0];
  const int*   ei = (const int*)d_in[1];   // [2, E]: first E = dst, next E = src
  const float* ew = (const float*)d_in[2];
  const float* W1 = (const float*)d_in[3];
  const float* W2 = (const float*)d_in[4];
  float* out = (float*)d_out;

  const int* dst = ei;
  const int* src = ei + N_EDGES;

  // ---- workspace: region1 is packed1 during build, h2 afterwards ----
  char* p = (char*)d_ws;
  int2*  packed1 = (int2*)p;
  float* h2      = (float*)p;  p += (size_t)N_EDGES * 8;              // 25.6 MB
  int2*  packed2 = (int2*)p;   p += (size_t)N_EDGES * 8;              // 25.6 MB
  float* h       = (float*)p;  p += (size_t)N_NODES * DIM_HID * 4;    // 25.6 MB
  int*   hist    = (int*)p;    p += (size_t)NBUCK * HPAD * 4;         // 100 KB
  int*   cursor  = (int*)p;    p += (size_t)NBUCK * HPAD * 4;         // 100 KB
  int*   base    = (int*)p;    p += (size_t)(NBUCK + 8) * 4;
  int*   ptr     = (int*)p;    p += (size_t)(N_NODES + 8) * 4;        // 400 KB

  // ---- build: bucket hist -> scan -> bucket scatter -> in-bucket sort ----
  hipMemsetAsync(hist, 0, (size_t)NBUCK * HPAD * 4, stream);
  hist_kernel<<<NCHUNK, 256, 0, stream>>>(dst, hist);
  scanb_kernel<<<1, 256, 0, stream>>>(hist, base, cursor, ptr);
  scatter_kernel<<<NCHUNK, 256, 0, stream>>>(dst, src, ew, cursor, packed1);
  sort2_kernel<<<NBUCK, 256, 0, stream>>>(base, packed1, packed2, ptr);

  // ---- layer 1 GEMM ----
  gemm1_kernel<<<N_NODES / 16, 256, 0, stream>>>(x, W1, h);

  // ---- SPMM1 + fused GEMM2 (h2 overwrites packed1 region; dead by now) ----
  spmm64_g2_kernel<<<N_NODES / 4, 256, 0, stream>>>(ptr, packed2, h, W2, h2);

  // ---- SPMM2 + fused log_softmax ----
  spmm40_lsm_kernel<<<N_NODES / 4, 256, 0, stream>>>(ptr, packed2, h2, out);
}

// Round 5
// 716.840 us; speedup vs baseline: 4.4466x; 1.0219x over previous
//
#include <hip/hip_runtime.h>
#include <hip/hip_bf16.h>
#include <math.h>

#define N_NODES 100000
#define N_EDGES 3200000
#define DIM_IN  128
#define DIM_HID 64
#define DIM_OUT 40

#define BSHIFT 6
#define BNODES 64
#define NBUCK ((N_NODES + BNODES - 1) / BNODES)   // 1563
#define HPAD  16                                  // counter stride: 64 B
#define CHUNK 4096
#define NCHUNK ((N_EDGES + CHUNK - 1) / CHUNK)    // 782

// ---- hist: per-WG LDS histogram of dst>>6, flushed to padded global counters
__global__ __launch_bounds__(256) void hist_kernel(
    const int* __restrict__ dst, int* __restrict__ hist) {
  __shared__ int cnt[NBUCK];
  const int t = threadIdx.x;
  for (int i = t; i < NBUCK; i += 256) cnt[i] = 0;
  __syncthreads();
  const int e0 = blockIdx.x * CHUNK;
  const int e1 = min(e0 + CHUNK, N_EDGES);
  for (int e = e0 + t; e < e1; e += 256) atomicAdd(&cnt[dst[e] >> BSHIFT], 1);
  __syncthreads();
  for (int i = t; i < NBUCK; i += 256) {
    const int c = cnt[i];
    if (c) atomicAdd(&hist[i * HPAD], c);
  }
}

// ---- exclusive scan of 1563 bucket counts (single block) -------------------
__global__ __launch_bounds__(256) void scanb_kernel(
    const int* __restrict__ hist, int* __restrict__ base,
    int* __restrict__ cursor, int* __restrict__ ptr) {
  const int t = threadIdx.x;
  int v[7]; int s = 0;
#pragma unroll
  for (int j = 0; j < 7; ++j) {
    const int i = t * 7 + j;
    v[j] = (i < NBUCK) ? hist[i * HPAD] : 0;
    s += v[j];
  }
  const int lane = t & 63, wid = t >> 6;
  int incl = s;
#pragma unroll
  for (int off = 1; off < 64; off <<= 1) {
    int n = __shfl_up(incl, off);
    if (lane >= off) incl += n;
  }
  __shared__ int wsum[4];
  if (lane == 63) wsum[wid] = incl;
  __syncthreads();
  int woff = 0;
  for (int k = 0; k < wid; ++k) woff += wsum[k];
  int run = woff + incl - s;
#pragma unroll
  for (int j = 0; j < 7; ++j) {
    const int i = t * 7 + j;
    if (i < NBUCK) { base[i] = run; cursor[i * HPAD] = run; }
    run += v[j];
  }
  if (t == 255) { base[NBUCK] = N_EDGES; ptr[N_NODES] = N_EDGES; }
}

// ---- scatter pass 1: edges -> bucket regions, per-WG LDS reservation -------
__global__ __launch_bounds__(256) void scatter_kernel(
    const int* __restrict__ dst, const int* __restrict__ src,
    const float* __restrict__ ew, int* __restrict__ cursor,
    int2* __restrict__ packed1) {
  __shared__ int cnt[NBUCK];
  const int t = threadIdx.x;
  for (int i = t; i < NBUCK; i += 256) cnt[i] = 0;
  __syncthreads();
  const int e0 = blockIdx.x * CHUNK;
  const int e1 = min(e0 + CHUNK, N_EDGES);
  for (int e = e0 + t; e < e1; e += 256) atomicAdd(&cnt[dst[e] >> BSHIFT], 1);
  __syncthreads();
  for (int i = t; i < NBUCK; i += 256) {
    const int c = cnt[i];
    cnt[i] = c ? atomicAdd(&cursor[i * HPAD], c) : 0;  // cnt becomes global cursor
  }
  __syncthreads();
  for (int e = e0 + t; e < e1; e += 256) {
    const int d = dst[e];
    const int pos = atomicAdd(&cnt[d >> BSHIFT], 1);
    int2 q;
    q.x = ((d & (BNODES - 1)) << 20) | src[e];   // src < 2^20
    q.y = __float_as_int(ew[e]);
    packed1[pos] = q;
  }
}

// ---- sort pass 2: within each bucket, order by node; emit ptr --------------
__global__ __launch_bounds__(256) void sort2_kernel(
    const int* __restrict__ base, const int2* __restrict__ packed1,
    int2* __restrict__ packed2, int* __restrict__ ptr) {
  __shared__ int cnt[BNODES];
  __shared__ int cur[BNODES];
  const int t = threadIdx.x;
  const int b = blockIdx.x;
  if (t < BNODES) cnt[t] = 0;
  const int e0 = base[b], e1 = base[b + 1];
  __syncthreads();
  for (int e = e0 + t; e < e1; e += 256)
    atomicAdd(&cnt[(packed1[e].x >> 20) & (BNODES - 1)], 1);
  __syncthreads();
  if (t < 64) {
    const int v = cnt[t];
    int incl = v;
#pragma unroll
    for (int off = 1; off < 64; off <<= 1) {
      int n = __shfl_up(incl, off);
      if (t >= off) incl += n;
    }
    const int start = e0 + incl - v;
    cur[t] = start;
    const int node = (b << BSHIFT) + t;
    if (node < N_NODES) ptr[node] = start;
  }
  __syncthreads();
  for (int e = e0 + t; e < e1; e += 256) {
    const int2 p = packed1[e];
    const int pos = atomicAdd(&cur[(p.x >> 20) & (BNODES - 1)], 1);
    int2 q; q.x = p.x & 0xFFFFF; q.y = p.y;
    packed2[pos] = q;
  }
}

// ---- GEMM1: h = x @ W1 (bf16 out), 16 rows/block -------------------------
__global__ __launch_bounds__(256) void gemm1_kernel(
    const float* __restrict__ x, const float* __restrict__ W1,
    __hip_bfloat16* __restrict__ h) {
  __shared__ float w[DIM_IN * DIM_HID];   // 32 KB
  for (int i = threadIdx.x; i < DIM_IN * DIM_HID; i += 256) w[i] = W1[i];
  __syncthreads();
  const int lane = threadIdx.x & 63, wid = threadIdx.x >> 6;
#pragma unroll
  for (int r = 0; r < 4; ++r) {
    const int row = blockIdx.x * 16 + r * 4 + wid;   // 100000 % 16 == 0
    const float4* xr = (const float4*)(x + (size_t)row * DIM_IN);
    float acc = 0.f;
#pragma unroll 8
    for (int k4 = 0; k4 < DIM_IN / 4; ++k4) {
      const float4 xv = xr[k4];
      acc = fmaf(xv.x, w[(k4 * 4 + 0) * DIM_HID + lane], acc);
      acc = fmaf(xv.y, w[(k4 * 4 + 1) * DIM_HID + lane], acc);
      acc = fmaf(xv.z, w[(k4 * 4 + 2) * DIM_HID + lane], acc);
      acc = fmaf(xv.w, w[(k4 * 4 + 3) * DIM_HID + lane], acc);
    }
    h[(size_t)row * DIM_HID + lane] = __float2bfloat16(acc);
  }
}

// ---- SPMM1 (CSR, wave/node, 8-way MLP, bf16 gather) + fused GEMM2 ---------
__global__ __launch_bounds__(256) void spmm64_g2_kernel(
    const int* __restrict__ ptr, const int2* __restrict__ packed,
    const __hip_bfloat16* __restrict__ h, const float* __restrict__ W2,
    __hip_bfloat16* __restrict__ h2) {
  __shared__ float w2[DIM_HID * DIM_OUT];   // 10 KB
  for (int i = threadIdx.x; i < DIM_HID * DIM_OUT; i += 256) w2[i] = W2[i];
  __syncthreads();
  const int node = blockIdx.x * 4 + (threadIdx.x >> 6);   // 25000*4 == N
  const int lane = threadIdx.x & 63;
  int e = ptr[node];
  const int end = ptr[node + 1];
  float acc = 0.f;
  for (; e + 8 <= end; e += 8) {
    const int2 p0 = packed[e],     p1 = packed[e + 1];
    const int2 p2 = packed[e + 2], p3 = packed[e + 3];
    const int2 p4 = packed[e + 4], p5 = packed[e + 5];
    const int2 p6 = packed[e + 6], p7 = packed[e + 7];
    const float a0 = (float)h[(size_t)p0.x * DIM_HID + lane];
    const float a1 = (float)h[(size_t)p1.x * DIM_HID + lane];
    const float a2 = (float)h[(size_t)p2.x * DIM_HID + lane];
    const float a3 = (float)h[(size_t)p3.x * DIM_HID + lane];
    const float a4 = (float)h[(size_t)p4.x * DIM_HID + lane];
    const float a5 = (float)h[(size_t)p5.x * DIM_HID + lane];
    const float a6 = (float)h[(size_t)p6.x * DIM_HID + lane];
    const float a7 = (float)h[(size_t)p7.x * DIM_HID + lane];
    acc = fmaf(__int_as_float(p0.y), a0, acc);
    acc = fmaf(__int_as_float(p1.y), a1, acc);
    acc = fmaf(__int_as_float(p2.y), a2, acc);
    acc = fmaf(__int_as_float(p3.y), a3, acc);
    acc = fmaf(__int_as_float(p4.y), a4, acc);
    acc = fmaf(__int_as_float(p5.y), a5, acc);
    acc = fmaf(__int_as_float(p6.y), a6, acc);
    acc = fmaf(__int_as_float(p7.y), a7, acc);
  }
  for (; e < end; ++e) {
    const int2 p = packed[e];
    acc = fmaf(__int_as_float(p.y), (float)h[(size_t)p.x * DIM_HID + lane], acc);
  }
  // fused GEMM2: h2[node, :] = relu(agg_row) @ W2 via lane broadcast
  const float r = fmaxf(acc, 0.f);
  const int c = (lane < DIM_OUT) ? lane : (DIM_OUT - 1);
  float s = 0.f;
#pragma unroll
  for (int k = 0; k < DIM_HID; ++k)
    s = fmaf(__shfl(r, k), w2[k * DIM_OUT + c], s);
  if (lane < DIM_OUT) h2[(size_t)node * DIM_OUT + lane] = __float2bfloat16(s);
}

// ---- SPMM2 (CSR, wave/node, 8-way MLP, bf16 gather) + fused log_softmax ----
__global__ __launch_bounds__(256) void spmm40_lsm_kernel(
    const int* __restrict__ ptr, const int2* __restrict__ packed,
    const __hip_bfloat16* __restrict__ h2, float* __restrict__ out) {
  const int node = blockIdx.x * 4 + (threadIdx.x >> 6);
  const int lane = threadIdx.x & 63;
  const int l = (lane < DIM_OUT) ? lane : (DIM_OUT - 1);
  int e = ptr[node];
  const int end = ptr[node + 1];
  float acc = 0.f;
  for (; e + 8 <= end; e += 8) {
    const int2 p0 = packed[e],     p1 = packed[e + 1];
    const int2 p2 = packed[e + 2], p3 = packed[e + 3];
    const int2 p4 = packed[e + 4], p5 = packed[e + 5];
    const int2 p6 = packed[e + 6], p7 = packed[e + 7];
    const float a0 = (float)h2[(size_t)p0.x * DIM_OUT + l];
    const float a1 = (float)h2[(size_t)p1.x * DIM_OUT + l];
    const float a2 = (float)h2[(size_t)p2.x * DIM_OUT + l];
    const float a3 = (float)h2[(size_t)p3.x * DIM_OUT + l];
    const float a4 = (float)h2[(size_t)p4.x * DIM_OUT + l];
    const float a5 = (float)h2[(size_t)p5.x * DIM_OUT + l];
    const float a6 = (float)h2[(size_t)p6.x * DIM_OUT + l];
    const float a7 = (float)h2[(size_t)p7.x * DIM_OUT + l];
    acc = fmaf(__int_as_float(p0.y), a0, acc);
    acc = fmaf(__int_as_float(p1.y), a1, acc);
    acc = fmaf(__int_as_float(p2.y), a2, acc);
    acc = fmaf(__int_as_float(p3.y), a3, acc);
    acc = fmaf(__int_as_float(p4.y), a4, acc);
    acc = fmaf(__int_as_float(p5.y), a5, acc);
    acc = fmaf(__int_as_float(p6.y), a6, acc);
    acc = fmaf(__int_as_float(p7.y), a7, acc);
  }
  for (; e < end; ++e) {
    const int2 p = packed[e];
    acc = fmaf(__int_as_float(p.y), (float)h2[(size_t)p.x * DIM_OUT + l], acc);
  }
  const bool act = (lane < DIM_OUT);
  const float v = act ? acc : -INFINITY;
  float m = v;
#pragma unroll
  for (int off = 32; off > 0; off >>= 1) m = fmaxf(m, __shfl_xor(m, off));
  const float ex = act ? expf(v - m) : 0.f;
  float s = ex;
#pragma unroll
  for (int off = 32; off > 0; off >>= 1) s += __shfl_xor(s, off);
  const float ls = logf(s);
  if (act) out[(size_t)node * DIM_OUT + lane] = v - m - ls;
}

extern "C" void kernel_launch(void* const* d_in, const int* in_sizes, int n_in,
                              void* d_out, int out_size, void* d_ws, size_t ws_size,
                              hipStream_t stream) {
  const float* x  = (const float*)d_in[0];
  const int*   ei = (const int*)d_in[1];   // [2, E]: first E = dst, next E = src
  const float* ew = (const float*)d_in[2];
  const float* W1 = (const float*)d_in[3];
  const float* W2 = (const float*)d_in[4];
  float* out = (float*)d_out;

  const int* dst = ei;
  const int* src = ei + N_EDGES;

  // ---- workspace: region1 is packed1 during build, h2 (bf16) afterwards ----
  char* p = (char*)d_ws;
  int2*           packed1 = (int2*)p;
  __hip_bfloat16* h2      = (__hip_bfloat16*)p;
  p += (size_t)N_EDGES * 8;                                     // 25.6 MB
  int2* packed2 = (int2*)p;  p += (size_t)N_EDGES * 8;          // 25.6 MB
  __hip_bfloat16* h = (__hip_bfloat16*)p;
  p += (size_t)N_NODES * DIM_HID * 2;                           // 12.8 MB
  int* hist   = (int*)p;  p += (size_t)NBUCK * HPAD * 4;        // 100 KB
  int* cursor = (int*)p;  p += (size_t)NBUCK * HPAD * 4;        // 100 KB
  int* base   = (int*)p;  p += (size_t)(NBUCK + 8) * 4;
  int* ptr    = (int*)p;  p += (size_t)(N_NODES + 8) * 4;       // 400 KB

  // ---- build: bucket hist -> scan -> bucket scatter -> in-bucket sort ----
  hipMemsetAsync(hist, 0, (size_t)NBUCK * HPAD * 4, stream);
  hist_kernel<<<NCHUNK, 256, 0, stream>>>(dst, hist);
  scanb_kernel<<<1, 256, 0, stream>>>(hist, base, cursor, ptr);
  scatter_kernel<<<NCHUNK, 256, 0, stream>>>(dst, src, ew, cursor, packed1);
  sort2_kernel<<<NBUCK, 256, 0, stream>>>(base, packed1, packed2, ptr);

  // ---- layer 1 GEMM (bf16 h) ----
  gemm1_kernel<<<N_NODES / 16, 256, 0, stream>>>(x, W1, h);

  // ---- SPMM1 + fused GEMM2 (h2 bf16 overwrites packed1; dead by now) ----
  spmm64_g2_kernel<<<N_NODES / 4, 256, 0, stream>>>(ptr, packed2, h, W2, h2);

  // ---- SPMM2 + fused log_softmax ----
  spmm40_lsm_kernel<<<N_NODES / 4, 256, 0, stream>>>(ptr, packed2, h2, out);
}

// Round 6
// 679.189 us; speedup vs baseline: 4.6931x; 1.0554x over previous
//
#include <hip/hip_runtime.h>
#include <hip/hip_bf16.h>
#include <math.h>

#define N_NODES 100000
#define N_EDGES 3200000
#define DIM_IN  128
#define DIM_HID 64
#define DIM_OUT 40

#define BSHIFT 6
#define BNODES 64
#define NBUCK ((N_NODES + BNODES - 1) / BNODES)   // 1563
#define HPAD  16                                  // counter stride: 64 B
#define CHUNK 4096
#define NCHUNK ((N_EDGES + CHUNK - 1) / CHUNK)    // 782

// ---- hist: per-WG LDS histogram of dst>>6, flushed to padded global counters
__global__ __launch_bounds__(256) void hist_kernel(
    const int* __restrict__ dst, int* __restrict__ hist) {
  __shared__ int cnt[NBUCK];
  const int t = threadIdx.x;
  for (int i = t; i < NBUCK; i += 256) cnt[i] = 0;
  __syncthreads();
  const int e0 = blockIdx.x * CHUNK;
  const int e1 = min(e0 + CHUNK, N_EDGES);
  for (int e = e0 + t; e < e1; e += 256) atomicAdd(&cnt[dst[e] >> BSHIFT], 1);
  __syncthreads();
  for (int i = t; i < NBUCK; i += 256) {
    const int c = cnt[i];
    if (c) atomicAdd(&hist[i * HPAD], c);
  }
}

// ---- exclusive scan of 1563 bucket counts (single block) -------------------
__global__ __launch_bounds__(256) void scanb_kernel(
    const int* __restrict__ hist, int* __restrict__ base,
    int* __restrict__ cursor, int* __restrict__ ptr) {
  const int t = threadIdx.x;
  int v[7]; int s = 0;
#pragma unroll
  for (int j = 0; j < 7; ++j) {
    const int i = t * 7 + j;
    v[j] = (i < NBUCK) ? hist[i * HPAD] : 0;
    s += v[j];
  }
  const int lane = t & 63, wid = t >> 6;
  int incl = s;
#pragma unroll
  for (int off = 1; off < 64; off <<= 1) {
    int n = __shfl_up(incl, off);
    if (lane >= off) incl += n;
  }
  __shared__ int wsum[4];
  if (lane == 63) wsum[wid] = incl;
  __syncthreads();
  int woff = 0;
  for (int k = 0; k < wid; ++k) woff += wsum[k];
  int run = woff + incl - s;
#pragma unroll
  for (int j = 0; j < 7; ++j) {
    const int i = t * 7 + j;
    if (i < NBUCK) { base[i] = run; cursor[i * HPAD] = run; }
    run += v[j];
  }
  if (t == 255) { base[NBUCK] = N_EDGES; ptr[N_NODES] = N_EDGES; }
}

// ---- scatter pass 1: edges -> bucket regions, per-WG LDS reservation -------
__global__ __launch_bounds__(256) void scatter_kernel(
    const int* __restrict__ dst, const int* __restrict__ src,
    const float* __restrict__ ew, int* __restrict__ cursor,
    int2* __restrict__ packed1) {
  __shared__ int cnt[NBUCK];
  const int t = threadIdx.x;
  for (int i = t; i < NBUCK; i += 256) cnt[i] = 0;
  __syncthreads();
  const int e0 = blockIdx.x * CHUNK;
  const int e1 = min(e0 + CHUNK, N_EDGES);
  for (int e = e0 + t; e < e1; e += 256) atomicAdd(&cnt[dst[e] >> BSHIFT], 1);
  __syncthreads();
  for (int i = t; i < NBUCK; i += 256) {
    const int c = cnt[i];
    cnt[i] = c ? atomicAdd(&cursor[i * HPAD], c) : 0;  // cnt becomes global cursor
  }
  __syncthreads();
  for (int e = e0 + t; e < e1; e += 256) {
    const int d = dst[e];
    const int pos = atomicAdd(&cnt[d >> BSHIFT], 1);
    int2 q;
    q.x = ((d & (BNODES - 1)) << 20) | src[e];   // src < 2^20
    q.y = __float_as_int(ew[e]);
    packed1[pos] = q;
  }
}

// ---- sort pass 2: within each bucket, order by node; emit ptr --------------
__global__ __launch_bounds__(256) void sort2_kernel(
    const int* __restrict__ base, const int2* __restrict__ packed1,
    int2* __restrict__ packed2, int* __restrict__ ptr) {
  __shared__ int cnt[BNODES];
  __shared__ int cur[BNODES];
  const int t = threadIdx.x;
  const int b = blockIdx.x;
  if (t < BNODES) cnt[t] = 0;
  const int e0 = base[b], e1 = base[b + 1];
  __syncthreads();
  for (int e = e0 + t; e < e1; e += 256)
    atomicAdd(&cnt[(packed1[e].x >> 20) & (BNODES - 1)], 1);
  __syncthreads();
  if (t < 64) {
    const int v = cnt[t];
    int incl = v;
#pragma unroll
    for (int off = 1; off < 64; off <<= 1) {
      int n = __shfl_up(incl, off);
      if (t >= off) incl += n;
    }
    const int start = e0 + incl - v;
    cur[t] = start;
    const int node = (b << BSHIFT) + t;
    if (node < N_NODES) ptr[node] = start;
  }
  __syncthreads();
  for (int e = e0 + t; e < e1; e += 256) {
    const int2 p = packed1[e];
    const int pos = atomicAdd(&cur[(p.x >> 20) & (BNODES - 1)], 1);
    int2 q; q.x = p.x & 0xFFFFF; q.y = p.y;
    packed2[pos] = q;
  }
}

// ---- GEMM1: h = x @ W1 (bf16 out), 16 rows/block -------------------------
__global__ __launch_bounds__(256) void gemm1_kernel(
    const float* __restrict__ x, const float* __restrict__ W1,
    __hip_bfloat16* __restrict__ h) {
  __shared__ float w[DIM_IN * DIM_HID];   // 32 KB
  for (int i = threadIdx.x; i < DIM_IN * DIM_HID; i += 256) w[i] = W1[i];
  __syncthreads();
  const int lane = threadIdx.x & 63, wid = threadIdx.x >> 6;
#pragma unroll
  for (int r = 0; r < 4; ++r) {
    const int row = blockIdx.x * 16 + r * 4 + wid;   // 100000 % 16 == 0
    const float4* xr = (const float4*)(x + (size_t)row * DIM_IN);
    float acc = 0.f;
#pragma unroll 8
    for (int k4 = 0; k4 < DIM_IN / 4; ++k4) {
      const float4 xv = xr[k4];
      acc = fmaf(xv.x, w[(k4 * 4 + 0) * DIM_HID + lane], acc);
      acc = fmaf(xv.y, w[(k4 * 4 + 1) * DIM_HID + lane], acc);
      acc = fmaf(xv.z, w[(k4 * 4 + 2) * DIM_HID + lane], acc);
      acc = fmaf(xv.w, w[(k4 * 4 + 3) * DIM_HID + lane], acc);
    }
    h[(size_t)row * DIM_HID + lane] = __float2bfloat16(acc);
  }
}

__device__ inline float bf_lo(unsigned int g) {
  return __uint_as_float(g << 16);
}
__device__ inline float bf_hi(unsigned int g) {
  return __uint_as_float(g & 0xFFFF0000u);
}

// ---- SPMM1 paired (2 edges/instr, 16 edges in flight) + fused GEMM2 --------
// Wave = 1 node. half = lane>>5 picks edge of a pair; hl = lane&31 covers the
// full 64-dim row as uint (2 bf16). acc0/acc1 = dims (2hl, 2hl+1) partials.
__global__ __launch_bounds__(256) void spmm64_g2_kernel(
    const int* __restrict__ ptr, const int2* __restrict__ packed,
    const __hip_bfloat16* __restrict__ hbf, const float* __restrict__ W2,
    __hip_bfloat16* __restrict__ h2) {   // h2 padded to width 64
  __shared__ float w2[DIM_HID * DIM_OUT];   // 10 KB
  for (int i = threadIdx.x; i < DIM_HID * DIM_OUT; i += 256) w2[i] = W2[i];
  __syncthreads();
  const unsigned short* __restrict__ h = (const unsigned short*)hbf;
  const int node = blockIdx.x * 4 + (threadIdx.x >> 6);   // 25000*4 == N
  const int lane = threadIdx.x & 63;
  const int half = lane >> 5, hl = lane & 31;
  int e = ptr[node];
  const int end = ptr[node + 1];
  float acc0 = 0.f, acc1 = 0.f;
  for (; e + 16 <= end; e += 16) {
    int2 p[8]; unsigned int g[8];
#pragma unroll
    for (int j = 0; j < 8; ++j) p[j] = packed[e + 2 * j + half];
#pragma unroll
    for (int j = 0; j < 8; ++j)
      g[j] = *(const unsigned int*)(h + (size_t)p[j].x * DIM_HID + hl * 2);
#pragma unroll
    for (int j = 0; j < 8; ++j) {
      const float w = __int_as_float(p[j].y);
      acc0 = fmaf(w, bf_lo(g[j]), acc0);
      acc1 = fmaf(w, bf_hi(g[j]), acc1);
    }
  }
  for (; e + 2 <= end; e += 2) {
    const int2 p = packed[e + half];
    const unsigned int g = *(const unsigned int*)(h + (size_t)p.x * DIM_HID + hl * 2);
    const float w = __int_as_float(p.y);
    acc0 = fmaf(w, bf_lo(g), acc0);
    acc1 = fmaf(w, bf_hi(g), acc1);
  }
  if (e < end) {
    const int2 p = packed[e];
    const unsigned int g = *(const unsigned int*)(h + (size_t)p.x * DIM_HID + hl * 2);
    const float w = half ? 0.f : __int_as_float(p.y);
    acc0 = fmaf(w, bf_lo(g), acc0);
    acc1 = fmaf(w, bf_hi(g), acc1);
  }
  // merge halves: every lane with index hl now holds full dims (2hl, 2hl+1)
  acc0 += __shfl_xor(acc0, 32);
  acc1 += __shfl_xor(acc1, 32);
  // fused GEMM2: s[c] = sum_k relu(agg[k]) * W2[k][c]
  const int c = (lane < DIM_OUT) ? lane : (DIM_OUT - 1);
  float s = 0.f;
#pragma unroll
  for (int k = 0; k < DIM_HID; k += 2) {
    const float v0 = fmaxf(__shfl(acc0, k >> 1), 0.f);
    const float v1 = fmaxf(__shfl(acc1, k >> 1), 0.f);
    s = fmaf(v0, w2[k * DIM_OUT + c], s);
    s = fmaf(v1, w2[(k + 1) * DIM_OUT + c], s);
  }
  // write padded row: dims 0..39 = s, dims 40..63 = 0
  h2[(size_t)node * 64 + lane] =
      __float2bfloat16((lane < DIM_OUT) ? s : 0.f);
}

// ---- SPMM2 paired (h2 padded to 64) + fused log_softmax --------------------
__global__ __launch_bounds__(256) void spmm40_lsm_kernel(
    const int* __restrict__ ptr, const int2* __restrict__ packed,
    const __hip_bfloat16* __restrict__ h2bf, float* __restrict__ out) {
  const unsigned short* __restrict__ h2 = (const unsigned short*)h2bf;
  const int node = blockIdx.x * 4 + (threadIdx.x >> 6);
  const int lane = threadIdx.x & 63;
  const int half = lane >> 5, hl = lane & 31;
  int e = ptr[node];
  const int end = ptr[node + 1];
  float acc0 = 0.f, acc1 = 0.f;
  for (; e + 16 <= end; e += 16) {
    int2 p[8]; unsigned int g[8];
#pragma unroll
    for (int j = 0; j < 8; ++j) p[j] = packed[e + 2 * j + half];
#pragma unroll
    for (int j = 0; j < 8; ++j)
      g[j] = *(const unsigned int*)(h2 + (size_t)p[j].x * 64 + hl * 2);
#pragma unroll
    for (int j = 0; j < 8; ++j) {
      const float w = __int_as_float(p[j].y);
      acc0 = fmaf(w, bf_lo(g[j]), acc0);
      acc1 = fmaf(w, bf_hi(g[j]), acc1);
    }
  }
  for (; e + 2 <= end; e += 2) {
    const int2 p = packed[e + half];
    const unsigned int g = *(const unsigned int*)(h2 + (size_t)p.x * 64 + hl * 2);
    const float w = __int_as_float(p.y);
    acc0 = fmaf(w, bf_lo(g), acc0);
    acc1 = fmaf(w, bf_hi(g), acc1);
  }
  if (e < end) {
    const int2 p = packed[e];
    const unsigned int g = *(const unsigned int*)(h2 + (size_t)p.x * 64 + hl * 2);
    const float w = half ? 0.f : __int_as_float(p.y);
    acc0 = fmaf(w, bf_lo(g), acc0);
    acc1 = fmaf(w, bf_hi(g), acc1);
  }
  acc0 += __shfl_xor(acc0, 32);
  acc1 += __shfl_xor(acc1, 32);
  // lane holds dims (2hl, 2hl+1); valid iff hl < 20 (dims < 40)
  const bool val = (hl < DIM_OUT / 2);
  float m = val ? fmaxf(acc0, acc1) : -INFINITY;
#pragma unroll
  for (int off = 16; off > 0; off >>= 1) m = fmaxf(m, __shfl_xor(m, off));
  const float ex = val ? (expf(acc0 - m) + expf(acc1 - m)) : 0.f;
  float s = ex;
#pragma unroll
  for (int off = 16; off > 0; off >>= 1) s += __shfl_xor(s, off);
  const float ls = logf(s);
  if (lane < DIM_OUT / 2) {
    float2 o;
    o.x = acc0 - m - ls;
    o.y = acc1 - m - ls;
    ((float2*)(out + (size_t)node * DIM_OUT))[hl] = o;
  }
}

extern "C" void kernel_launch(void* const* d_in, const int* in_sizes, int n_in,
                              void* d_out, int out_size, void* d_ws, size_t ws_size,
                              hipStream_t stream) {
  const float* x  = (const float*)d_in[0];
  const int*   ei = (const int*)d_in[1];   // [2, E]: first E = dst, next E = src
  const float* ew = (const float*)d_in[2];
  const float* W1 = (const float*)d_in[3];
  const float* W2 = (const float*)d_in[4];
  float* out = (float*)d_out;

  const int* dst = ei;
  const int* src = ei + N_EDGES;

  // ---- workspace: region1 is packed1 during build, h2 (bf16 x64) after ----
  char* p = (char*)d_ws;
  int2*           packed1 = (int2*)p;
  __hip_bfloat16* h2      = (__hip_bfloat16*)p;   // N*64 bf16 = 12.8 MB
  p += (size_t)N_EDGES * 8;                                     // 25.6 MB
  int2* packed2 = (int2*)p;  p += (size_t)N_EDGES * 8;          // 25.6 MB
  __hip_bfloat16* h = (__hip_bfloat16*)p;
  p += (size_t)N_NODES * DIM_HID * 2;                           // 12.8 MB
  int* hist   = (int*)p;  p += (size_t)NBUCK * HPAD * 4;        // 100 KB
  int* cursor = (int*)p;  p += (size_t)NBUCK * HPAD * 4;        // 100 KB
  int* base   = (int*)p;  p += (size_t)(NBUCK + 8) * 4;
  int* ptr    = (int*)p;  p += (size_t)(N_NODES + 8) * 4;       // 400 KB

  // ---- build: bucket hist -> scan -> bucket scatter -> in-bucket sort ----
  hipMemsetAsync(hist, 0, (size_t)NBUCK * HPAD * 4, stream);
  hist_kernel<<<NCHUNK, 256, 0, stream>>>(dst, hist);
  scanb_kernel<<<1, 256, 0, stream>>>(hist, base, cursor, ptr);
  scatter_kernel<<<NCHUNK, 256, 0, stream>>>(dst, src, ew, cursor, packed1);
  sort2_kernel<<<NBUCK, 256, 0, stream>>>(base, packed1, packed2, ptr);

  // ---- layer 1 GEMM (bf16 h) ----
  gemm1_kernel<<<N_NODES / 16, 256, 0, stream>>>(x, W1, h);

  // ---- SPMM1 + fused GEMM2 (h2 overwrites packed1; dead by now) ----
  spmm64_g2_kernel<<<N_NODES / 4, 256, 0, stream>>>(ptr, packed2, h, W2, h2);

  // ---- SPMM2 + fused log_softmax ----
  spmm40_lsm_kernel<<<N_NODES / 4, 256, 0, stream>>>(ptr, packed2, h2, out);
}

// Round 7
// 647.224 us; speedup vs baseline: 4.9249x; 1.0494x over previous
//
#include <hip/hip_runtime.h>
#include <hip/hip_bf16.h>
#include <math.h>

#define N_NODES 100000
#define N_EDGES 3200000
#define DIM_IN  128
#define DIM_HID 64
#define DIM_OUT 40

#define BSHIFT 6
#define BNODES 64
#define NBUCK ((N_NODES + BNODES - 1) / BNODES)   // 1563
#define HPAD  16                                  // counter stride: 64 B
#define CHUNK 4096
#define NCHUNK ((N_EDGES + CHUNK - 1) / CHUNK)    // 782

// ---- hist: per-WG LDS histogram of dst>>6, flushed to padded global counters
__global__ __launch_bounds__(256) void hist_kernel(
    const int* __restrict__ dst, int* __restrict__ hist) {
  __shared__ int cnt[NBUCK];
  const int t = threadIdx.x;
  for (int i = t; i < NBUCK; i += 256) cnt[i] = 0;
  __syncthreads();
  const int e0 = blockIdx.x * CHUNK;
  const int e1 = min(e0 + CHUNK, N_EDGES);
  for (int e = e0 + t; e < e1; e += 256) atomicAdd(&cnt[dst[e] >> BSHIFT], 1);
  __syncthreads();
  for (int i = t; i < NBUCK; i += 256) {
    const int c = cnt[i];
    if (c) atomicAdd(&hist[i * HPAD], c);
  }
}

// ---- exclusive scan of 1563 bucket counts (single block) -------------------
__global__ __launch_bounds__(256) void scanb_kernel(
    const int* __restrict__ hist, int* __restrict__ base,
    int* __restrict__ cursor, int* __restrict__ ptr) {
  const int t = threadIdx.x;
  int v[7]; int s = 0;
#pragma unroll
  for (int j = 0; j < 7; ++j) {
    const int i = t * 7 + j;
    v[j] = (i < NBUCK) ? hist[i * HPAD] : 0;
    s += v[j];
  }
  const int lane = t & 63, wid = t >> 6;
  int incl = s;
#pragma unroll
  for (int off = 1; off < 64; off <<= 1) {
    int n = __shfl_up(incl, off);
    if (lane >= off) incl += n;
  }
  __shared__ int wsum[4];
  if (lane == 63) wsum[wid] = incl;
  __syncthreads();
  int woff = 0;
  for (int k = 0; k < wid; ++k) woff += wsum[k];
  int run = woff + incl - s;
#pragma unroll
  for (int j = 0; j < 7; ++j) {
    const int i = t * 7 + j;
    if (i < NBUCK) { base[i] = run; cursor[i * HPAD] = run; }
    run += v[j];
  }
  if (t == 255) { base[NBUCK] = N_EDGES; ptr[N_NODES] = N_EDGES; }
}

// ---- scatter pass 1: edges -> bucket regions, per-WG LDS reservation -------
__global__ __launch_bounds__(256) void scatter_kernel(
    const int* __restrict__ dst, const int* __restrict__ src,
    const float* __restrict__ ew, int* __restrict__ cursor,
    int2* __restrict__ packed1) {
  __shared__ int cnt[NBUCK];
  const int t = threadIdx.x;
  for (int i = t; i < NBUCK; i += 256) cnt[i] = 0;
  __syncthreads();
  const int e0 = blockIdx.x * CHUNK;
  const int e1 = min(e0 + CHUNK, N_EDGES);
  for (int e = e0 + t; e < e1; e += 256) atomicAdd(&cnt[dst[e] >> BSHIFT], 1);
  __syncthreads();
  for (int i = t; i < NBUCK; i += 256) {
    const int c = cnt[i];
    cnt[i] = c ? atomicAdd(&cursor[i * HPAD], c) : 0;  // cnt becomes global cursor
  }
  __syncthreads();
  for (int e = e0 + t; e < e1; e += 256) {
    const int d = dst[e];
    const int pos = atomicAdd(&cnt[d >> BSHIFT], 1);
    int2 q;
    q.x = ((d & (BNODES - 1)) << 20) | src[e];   // src < 2^20
    q.y = __float_as_int(ew[e]);
    packed1[pos] = q;
  }
}

// ---- sort pass 2: within each bucket, order by node; emit ptr --------------
__global__ __launch_bounds__(256) void sort2_kernel(
    const int* __restrict__ base, const int2* __restrict__ packed1,
    int2* __restrict__ packed2, int* __restrict__ ptr) {
  __shared__ int cnt[BNODES];
  __shared__ int cur[BNODES];
  const int t = threadIdx.x;
  const int b = blockIdx.x;
  if (t < BNODES) cnt[t] = 0;
  const int e0 = base[b], e1 = base[b + 1];
  __syncthreads();
  for (int e = e0 + t; e < e1; e += 256)
    atomicAdd(&cnt[(packed1[e].x >> 20) & (BNODES - 1)], 1);
  __syncthreads();
  if (t < 64) {
    const int v = cnt[t];
    int incl = v;
#pragma unroll
    for (int off = 1; off < 64; off <<= 1) {
      int n = __shfl_up(incl, off);
      if (t >= off) incl += n;
    }
    const int start = e0 + incl - v;
    cur[t] = start;
    const int node = (b << BSHIFT) + t;
    if (node < N_NODES) ptr[node] = start;
  }
  __syncthreads();
  for (int e = e0 + t; e < e1; e += 256) {
    const int2 p = packed1[e];
    const int pos = atomicAdd(&cur[(p.x >> 20) & (BNODES - 1)], 1);
    int2 q; q.x = p.x & 0xFFFFF; q.y = p.y;
    packed2[pos] = q;
  }
}

// ---- GEMM1: h = x @ W1 (bf16 out), 16 rows/block -------------------------
__global__ __launch_bounds__(256) void gemm1_kernel(
    const float* __restrict__ x, const float* __restrict__ W1,
    __hip_bfloat16* __restrict__ h) {
  __shared__ float w[DIM_IN * DIM_HID];   // 32 KB
  for (int i = threadIdx.x; i < DIM_IN * DIM_HID; i += 256) w[i] = W1[i];
  __syncthreads();
  const int lane = threadIdx.x & 63, wid = threadIdx.x >> 6;
#pragma unroll
  for (int r = 0; r < 4; ++r) {
    const int row = blockIdx.x * 16 + r * 4 + wid;   // 100000 % 16 == 0
    const float4* xr = (const float4*)(x + (size_t)row * DIM_IN);
    float acc = 0.f;
#pragma unroll 8
    for (int k4 = 0; k4 < DIM_IN / 4; ++k4) {
      const float4 xv = xr[k4];
      acc = fmaf(xv.x, w[(k4 * 4 + 0) * DIM_HID + lane], acc);
      acc = fmaf(xv.y, w[(k4 * 4 + 1) * DIM_HID + lane], acc);
      acc = fmaf(xv.z, w[(k4 * 4 + 2) * DIM_HID + lane], acc);
      acc = fmaf(xv.w, w[(k4 * 4 + 3) * DIM_HID + lane], acc);
    }
    h[(size_t)row * DIM_HID + lane] = __float2bfloat16(acc);
  }
}

__device__ inline float bf_lo(unsigned int g) {
  return __uint_as_float(g << 16);
}
__device__ inline float bf_hi(unsigned int g) {
  return __uint_as_float(g & 0xFFFF0000u);
}

// ---- SPMM1 paired + fully-predicated 16-edge iterations + fused GEMM2 ------
// Wave = 1 node (scalar wave id via readfirstlane so edge-list reads are
// wave-uniform). half = lane>>5 picks edge of a pair; hl = lane&31 covers the
// 64-dim row as uint (2 bf16). Tail is predicated, not serialized.
__global__ __launch_bounds__(256) void spmm64_g2_kernel(
    const int* __restrict__ ptr, const int2* __restrict__ packed,
    const __hip_bfloat16* __restrict__ hbf, const float* __restrict__ W2,
    __hip_bfloat16* __restrict__ h2) {   // h2 padded to width 64
  __shared__ float w2[DIM_HID * DIM_OUT];   // 10 KB
  for (int i = threadIdx.x; i < DIM_HID * DIM_OUT; i += 256) w2[i] = W2[i];
  __syncthreads();
  const unsigned short* __restrict__ h = (const unsigned short*)hbf;
  const int wv = __builtin_amdgcn_readfirstlane(threadIdx.x) >> 6;  // scalar
  const int node = blockIdx.x * 4 + wv;                 // 25000*4 == N
  const int lane = threadIdx.x & 63;
  const int half = lane >> 5, hl = lane & 31;
  const int eb = ptr[node];
  const int ee = ptr[node + 1];
  float acc0 = 0.f, acc1 = 0.f;
  for (int e = eb; e < ee; e += 16) {
#pragma unroll
    for (int j = 0; j < 8; ++j) {
      const int4 q = *(const int4*)(packed + e + 2 * j);  // wave-uniform addr
      const int slot = e + 2 * j + half;
      const bool val = slot < ee;
      const int sa = val ? (half ? q.z : q.x) : 0;
      const float wgt = val ? __int_as_float(half ? q.w : q.y) : 0.f;
      const unsigned int g =
          *(const unsigned int*)(h + (size_t)sa * DIM_HID + hl * 2);
      acc0 = fmaf(wgt, bf_lo(g), acc0);
      acc1 = fmaf(wgt, bf_hi(g), acc1);
    }
  }
  // merge halves: lane hl now holds full dims (2hl, 2hl+1)
  acc0 += __shfl_xor(acc0, 32);
  acc1 += __shfl_xor(acc1, 32);
  // fused GEMM2: s[c] = sum_k relu(agg[k]) * W2[k][c]
  const int c = (lane < DIM_OUT) ? lane : (DIM_OUT - 1);
  float s = 0.f;
#pragma unroll
  for (int k = 0; k < DIM_HID; k += 2) {
    const float v0 = fmaxf(__shfl(acc0, k >> 1), 0.f);
    const float v1 = fmaxf(__shfl(acc1, k >> 1), 0.f);
    s = fmaf(v0, w2[k * DIM_OUT + c], s);
    s = fmaf(v1, w2[(k + 1) * DIM_OUT + c], s);
  }
  // write padded row: dims 0..39 = s, dims 40..63 = 0
  h2[(size_t)node * 64 + lane] =
      __float2bfloat16((lane < DIM_OUT) ? s : 0.f);
}

// ---- SPMM2 paired + predicated (h2 padded to 64) + fused log_softmax -------
__global__ __launch_bounds__(256) void spmm40_lsm_kernel(
    const int* __restrict__ ptr, const int2* __restrict__ packed,
    const __hip_bfloat16* __restrict__ h2bf, float* __restrict__ out) {
  const unsigned short* __restrict__ h2 = (const unsigned short*)h2bf;
  const int wv = __builtin_amdgcn_readfirstlane(threadIdx.x) >> 6;  // scalar
  const int node = blockIdx.x * 4 + wv;
  const int lane = threadIdx.x & 63;
  const int half = lane >> 5, hl = lane & 31;
  const int eb = ptr[node];
  const int ee = ptr[node + 1];
  float acc0 = 0.f, acc1 = 0.f;
  for (int e = eb; e < ee; e += 16) {
#pragma unroll
    for (int j = 0; j < 8; ++j) {
      const int4 q = *(const int4*)(packed + e + 2 * j);  // wave-uniform addr
      const int slot = e + 2 * j + half;
      const bool val = slot < ee;
      const int sa = val ? (half ? q.z : q.x) : 0;
      const float wgt = val ? __int_as_float(half ? q.w : q.y) : 0.f;
      const unsigned int g =
          *(const unsigned int*)(h2 + (size_t)sa * 64 + hl * 2);
      acc0 = fmaf(wgt, bf_lo(g), acc0);
      acc1 = fmaf(wgt, bf_hi(g), acc1);
    }
  }
  acc0 += __shfl_xor(acc0, 32);
  acc1 += __shfl_xor(acc1, 32);
  // lane holds dims (2hl, 2hl+1); valid iff hl < 20 (dims < 40)
  const bool val = (hl < DIM_OUT / 2);
  float m = val ? fmaxf(acc0, acc1) : -INFINITY;
#pragma unroll
  for (int off = 16; off > 0; off >>= 1) m = fmaxf(m, __shfl_xor(m, off));
  const float ex = val ? (expf(acc0 - m) + expf(acc1 - m)) : 0.f;
  float s = ex;
#pragma unroll
  for (int off = 16; off > 0; off >>= 1) s += __shfl_xor(s, off);
  const float ls = logf(s);
  if (lane < DIM_OUT / 2) {
    float2 o;
    o.x = acc0 - m - ls;
    o.y = acc1 - m - ls;
    ((float2*)(out + (size_t)node * DIM_OUT))[hl] = o;
  }
}

extern "C" void kernel_launch(void* const* d_in, const int* in_sizes, int n_in,
                              void* d_out, int out_size, void* d_ws, size_t ws_size,
                              hipStream_t stream) {
  const float* x  = (const float*)d_in[0];
  const int*   ei = (const int*)d_in[1];   // [2, E]: first E = dst, next E = src
  const float* ew = (const float*)d_in[2];
  const float* W1 = (const float*)d_in[3];
  const float* W2 = (const float*)d_in[4];
  float* out = (float*)d_out;

  const int* dst = ei;
  const int* src = ei + N_EDGES;

  // ---- workspace: region1 is packed1 during build, h2 (bf16 x64) after ----
  char* p = (char*)d_ws;
  int2*           packed1 = (int2*)p;
  __hip_bfloat16* h2      = (__hip_bfloat16*)p;   // N*64 bf16 = 12.8 MB
  p += (size_t)N_EDGES * 8;                                     // 25.6 MB
  int2* packed2 = (int2*)p;  p += (size_t)(N_EDGES + 16) * 8;   // 25.6 MB + pad
  __hip_bfloat16* h = (__hip_bfloat16*)p;
  p += (size_t)N_NODES * DIM_HID * 2;                           // 12.8 MB
  int* hist   = (int*)p;  p += (size_t)NBUCK * HPAD * 4;        // 100 KB
  int* cursor = (int*)p;  p += (size_t)NBUCK * HPAD * 4;        // 100 KB
  int* base   = (int*)p;  p += (size_t)(NBUCK + 8) * 4;
  int* ptr    = (int*)p;  p += (size_t)(N_NODES + 8) * 4;       // 400 KB

  // ---- build: bucket hist -> scan -> bucket scatter -> in-bucket sort ----
  hipMemsetAsync(hist, 0, (size_t)NBUCK * HPAD * 4, stream);
  hist_kernel<<<NCHUNK, 256, 0, stream>>>(dst, hist);
  scanb_kernel<<<1, 256, 0, stream>>>(hist, base, cursor, ptr);
  scatter_kernel<<<NCHUNK, 256, 0, stream>>>(dst, src, ew, cursor, packed1);
  sort2_kernel<<<NBUCK, 256, 0, stream>>>(base, packed1, packed2, ptr);

  // ---- layer 1 GEMM (bf16 h) ----
  gemm1_kernel<<<N_NODES / 16, 256, 0, stream>>>(x, W1, h);

  // ---- SPMM1 + fused GEMM2 (h2 overwrites packed1; dead by now) ----
  spmm64_g2_kernel<<<N_NODES / 4, 256, 0, stream>>>(ptr, packed2, h, W2, h2);

  // ---- SPMM2 + fused log_softmax ----
  spmm40_lsm_kernel<<<N_NODES / 4, 256, 0, stream>>>(ptr, packed2, h2, out);
}

// Round 8
// 623.290 us; speedup vs baseline: 5.1140x; 1.0384x over previous
//
#include <hip/hip_runtime.h>
#include <hip/hip_bf16.h>
#include <math.h>

#define N_NODES 100000
#define N_EDGES 3200000
#define DIM_IN  128
#define DIM_HID 64
#define DIM_OUT 40

#define BSHIFT 6
#define BNODES 64
#define NBUCK ((N_NODES + BNODES - 1) / BNODES)   // 1563
#define HPAD  16                                  // counter stride: 64 B
#define CHUNK 4096
#define NCHUNK ((N_EDGES + CHUNK - 1) / CHUNK)    // 782

// ---- hist: per-WG LDS histogram of dst>>6, flushed to padded global counters
__global__ __launch_bounds__(256) void hist_kernel(
    const int* __restrict__ dst, int* __restrict__ hist) {
  __shared__ int cnt[NBUCK];
  const int t = threadIdx.x;
  for (int i = t; i < NBUCK; i += 256) cnt[i] = 0;
  __syncthreads();
  const int e0 = blockIdx.x * CHUNK;
  const int e1 = min(e0 + CHUNK, N_EDGES);
  for (int e = e0 + t; e < e1; e += 256) atomicAdd(&cnt[dst[e] >> BSHIFT], 1);
  __syncthreads();
  for (int i = t; i < NBUCK; i += 256) {
    const int c = cnt[i];
    if (c) atomicAdd(&hist[i * HPAD], c);
  }
}

// ---- exclusive scan of 1563 bucket counts (single block) -------------------
__global__ __launch_bounds__(256) void scanb_kernel(
    const int* __restrict__ hist, int* __restrict__ base,
    int* __restrict__ cursor, int* __restrict__ ptr) {
  const int t = threadIdx.x;
  int v[7]; int s = 0;
#pragma unroll
  for (int j = 0; j < 7; ++j) {
    const int i = t * 7 + j;
    v[j] = (i < NBUCK) ? hist[i * HPAD] : 0;
    s += v[j];
  }
  const int lane = t & 63, wid = t >> 6;
  int incl = s;
#pragma unroll
  for (int off = 1; off < 64; off <<= 1) {
    int n = __shfl_up(incl, off);
    if (lane >= off) incl += n;
  }
  __shared__ int wsum[4];
  if (lane == 63) wsum[wid] = incl;
  __syncthreads();
  int woff = 0;
  for (int k = 0; k < wid; ++k) woff += wsum[k];
  int run = woff + incl - s;
#pragma unroll
  for (int j = 0; j < 7; ++j) {
    const int i = t * 7 + j;
    if (i < NBUCK) { base[i] = run; cursor[i * HPAD] = run; }
    run += v[j];
  }
  if (t == 255) { base[NBUCK] = N_EDGES; ptr[N_NODES] = N_EDGES; }
}

// ---- scatter pass 1: edges -> bucket regions, per-WG LDS reservation -------
__global__ __launch_bounds__(256) void scatter_kernel(
    const int* __restrict__ dst, const int* __restrict__ src,
    const float* __restrict__ ew, int* __restrict__ cursor,
    int2* __restrict__ packed1) {
  __shared__ int cnt[NBUCK];
  const int t = threadIdx.x;
  for (int i = t; i < NBUCK; i += 256) cnt[i] = 0;
  __syncthreads();
  const int e0 = blockIdx.x * CHUNK;
  const int e1 = min(e0 + CHUNK, N_EDGES);
  for (int e = e0 + t; e < e1; e += 256) atomicAdd(&cnt[dst[e] >> BSHIFT], 1);
  __syncthreads();
  for (int i = t; i < NBUCK; i += 256) {
    const int c = cnt[i];
    cnt[i] = c ? atomicAdd(&cursor[i * HPAD], c) : 0;  // cnt becomes global cursor
  }
  __syncthreads();
  for (int e = e0 + t; e < e1; e += 256) {
    const int d = dst[e];
    const int pos = atomicAdd(&cnt[d >> BSHIFT], 1);
    int2 q;
    q.x = ((d & (BNODES - 1)) << 20) | src[e];   // src < 2^20
    q.y = __float_as_int(ew[e]);
    packed1[pos] = q;
  }
}

// ---- sort pass 2: within each bucket, order by node; emit ptr --------------
__global__ __launch_bounds__(256) void sort2_kernel(
    const int* __restrict__ base, const int2* __restrict__ packed1,
    int2* __restrict__ packed2, int* __restrict__ ptr) {
  __shared__ int cnt[BNODES];
  __shared__ int cur[BNODES];
  const int t = threadIdx.x;
  const int b = blockIdx.x;
  if (t < BNODES) cnt[t] = 0;
  const int e0 = base[b], e1 = base[b + 1];
  __syncthreads();
  for (int e = e0 + t; e < e1; e += 256)
    atomicAdd(&cnt[(packed1[e].x >> 20) & (BNODES - 1)], 1);
  __syncthreads();
  if (t < 64) {
    const int v = cnt[t];
    int incl = v;
#pragma unroll
    for (int off = 1; off < 64; off <<= 1) {
      int n = __shfl_up(incl, off);
      if (t >= off) incl += n;
    }
    const int start = e0 + incl - v;
    cur[t] = start;
    const int node = (b << BSHIFT) + t;
    if (node < N_NODES) ptr[node] = start;
  }
  __syncthreads();
  for (int e = e0 + t; e < e1; e += 256) {
    const int2 p = packed1[e];
    const int pos = atomicAdd(&cur[(p.x >> 20) & (BNODES - 1)], 1);
    int2 q; q.x = p.x & 0xFFFFF; q.y = p.y;
    packed2[pos] = q;
  }
}

// ---- GEMM1: h = x @ W1 (bf16 out), 16 rows/block -------------------------
__global__ __launch_bounds__(256) void gemm1_kernel(
    const float* __restrict__ x, const float* __restrict__ W1,
    __hip_bfloat16* __restrict__ h) {
  __shared__ float w[DIM_IN * DIM_HID];   // 32 KB
  for (int i = threadIdx.x; i < DIM_IN * DIM_HID; i += 256) w[i] = W1[i];
  __syncthreads();
  const int lane = threadIdx.x & 63, wid = threadIdx.x >> 6;
#pragma unroll
  for (int r = 0; r < 4; ++r) {
    const int row = blockIdx.x * 16 + r * 4 + wid;   // 100000 % 16 == 0
    const float4* xr = (const float4*)(x + (size_t)row * DIM_IN);
    float acc = 0.f;
#pragma unroll 8
    for (int k4 = 0; k4 < DIM_IN / 4; ++k4) {
      const float4 xv = xr[k4];
      acc = fmaf(xv.x, w[(k4 * 4 + 0) * DIM_HID + lane], acc);
      acc = fmaf(xv.y, w[(k4 * 4 + 1) * DIM_HID + lane], acc);
      acc = fmaf(xv.z, w[(k4 * 4 + 2) * DIM_HID + lane], acc);
      acc = fmaf(xv.w, w[(k4 * 4 + 3) * DIM_HID + lane], acc);
    }
    h[(size_t)row * DIM_HID + lane] = __float2bfloat16(acc);
  }
}

__device__ inline float bf_lo(unsigned int g) {
  return __uint_as_float(g << 16);
}
__device__ inline float bf_hi(unsigned int g) {
  return __uint_as_float(g & 0xFFFF0000u);
}

// ---- SPMM1: clean 16-edge main loop + one predicated tail block ------------
// Wave = 1 node. half = lane>>5 picks edge of a pair; hl = lane&31 covers the
// 64-dim bf16 row (128 B) as uint. 32-bit byte-offset addressing.
__global__ __launch_bounds__(256) void spmm64_g2_kernel(
    const int* __restrict__ ptr, const int2* __restrict__ packed,
    const __hip_bfloat16* __restrict__ hbf, const float* __restrict__ W2,
    __hip_bfloat16* __restrict__ h2) {   // h2 padded to width 64
  __shared__ float w2[DIM_HID * DIM_OUT];   // 10 KB
  for (int i = threadIdx.x; i < DIM_HID * DIM_OUT; i += 256) w2[i] = W2[i];
  __syncthreads();
  const char* __restrict__ hb = (const char*)hbf;
  const int wv = __builtin_amdgcn_readfirstlane(threadIdx.x) >> 6;  // scalar
  const int node = blockIdx.x * 4 + wv;                 // 25000*4 == N
  const int lane = threadIdx.x & 63;
  const int half = lane >> 5, hl = lane & 31;
  const unsigned int voff = (unsigned int)hl * 4u;      // byte offset in row
  const int eb = ptr[node];
  const int ee = ptr[node + 1];
  float acc0 = 0.f, acc1 = 0.f;
  int e = eb;
  for (; e + 16 <= ee; e += 16) {      // clean main loop: no predication
#pragma unroll
    for (int j = 0; j < 8; ++j) {
      const int4 q = *(const int4*)(packed + e + 2 * j);  // wave-uniform
      const int sa = half ? q.z : q.x;
      const float wgt = __int_as_float(half ? q.w : q.y);
      const unsigned int g =
          *(const unsigned int*)(hb + (((unsigned int)sa << 7) + voff));
      acc0 = fmaf(wgt, bf_lo(g), acc0);
      acc1 = fmaf(wgt, bf_hi(g), acc1);
    }
  }
  if (e < ee) {                        // single predicated tail block
#pragma unroll
    for (int j = 0; j < 8; ++j) {
      const int4 q = *(const int4*)(packed + e + 2 * j);  // padded array
      const bool val = (e + 2 * j + half) < ee;
      const int sa = val ? (half ? q.z : q.x) : 0;
      const float wgt = val ? __int_as_float(half ? q.w : q.y) : 0.f;
      const unsigned int g =
          *(const unsigned int*)(hb + (((unsigned int)sa << 7) + voff));
      acc0 = fmaf(wgt, bf_lo(g), acc0);
      acc1 = fmaf(wgt, bf_hi(g), acc1);
    }
  }
  // merge halves: lane hl now holds full dims (2hl, 2hl+1)
  acc0 += __shfl_xor(acc0, 32);
  acc1 += __shfl_xor(acc1, 32);
  // fused GEMM2: s[c] = sum_k relu(agg[k]) * W2[k][c]
  const int c = (lane < DIM_OUT) ? lane : (DIM_OUT - 1);
  float s = 0.f;
#pragma unroll
  for (int k = 0; k < DIM_HID; k += 2) {
    const float v0 = fmaxf(__shfl(acc0, k >> 1), 0.f);
    const float v1 = fmaxf(__shfl(acc1, k >> 1), 0.f);
    s = fmaf(v0, w2[k * DIM_OUT + c], s);
    s = fmaf(v1, w2[(k + 1) * DIM_OUT + c], s);
  }
  // write padded row: dims 0..39 = s, dims 40..63 = 0
  h2[(size_t)node * 64 + lane] =
      __float2bfloat16((lane < DIM_OUT) ? s : 0.f);
}

// ---- SPMM2 (h2 padded to 64) same structure + fused log_softmax ------------
__global__ __launch_bounds__(256) void spmm40_lsm_kernel(
    const int* __restrict__ ptr, const int2* __restrict__ packed,
    const __hip_bfloat16* __restrict__ h2bf, float* __restrict__ out) {
  const char* __restrict__ hb = (const char*)h2bf;
  const int wv = __builtin_amdgcn_readfirstlane(threadIdx.x) >> 6;  // scalar
  const int node = blockIdx.x * 4 + wv;
  const int lane = threadIdx.x & 63;
  const int half = lane >> 5, hl = lane & 31;
  const unsigned int voff = (unsigned int)hl * 4u;
  const int eb = ptr[node];
  const int ee = ptr[node + 1];
  float acc0 = 0.f, acc1 = 0.f;
  int e = eb;
  for (; e + 16 <= ee; e += 16) {
#pragma unroll
    for (int j = 0; j < 8; ++j) {
      const int4 q = *(const int4*)(packed + e + 2 * j);
      const int sa = half ? q.z : q.x;
      const float wgt = __int_as_float(half ? q.w : q.y);
      const unsigned int g =
          *(const unsigned int*)(hb + (((unsigned int)sa << 7) + voff));
      acc0 = fmaf(wgt, bf_lo(g), acc0);
      acc1 = fmaf(wgt, bf_hi(g), acc1);
    }
  }
  if (e < ee) {
#pragma unroll
    for (int j = 0; j < 8; ++j) {
      const int4 q = *(const int4*)(packed + e + 2 * j);
      const bool val = (e + 2 * j + half) < ee;
      const int sa = val ? (half ? q.z : q.x) : 0;
      const float wgt = val ? __int_as_float(half ? q.w : q.y) : 0.f;
      const unsigned int g =
          *(const unsigned int*)(hb + (((unsigned int)sa << 7) + voff));
      acc0 = fmaf(wgt, bf_lo(g), acc0);
      acc1 = fmaf(wgt, bf_hi(g), acc1);
    }
  }
  acc0 += __shfl_xor(acc0, 32);
  acc1 += __shfl_xor(acc1, 32);
  // lane holds dims (2hl, 2hl+1); valid iff hl < 20 (dims < 40)
  const bool val = (hl < DIM_OUT / 2);
  float m = val ? fmaxf(acc0, acc1) : -INFINITY;
#pragma unroll
  for (int off = 16; off > 0; off >>= 1) m = fmaxf(m, __shfl_xor(m, off));
  const float ex = val ? (expf(acc0 - m) + expf(acc1 - m)) : 0.f;
  float s = ex;
#pragma unroll
  for (int off = 16; off > 0; off >>= 1) s += __shfl_xor(s, off);
  const float ls = logf(s);
  if (lane < DIM_OUT / 2) {
    float2 o;
    o.x = acc0 - m - ls;
    o.y = acc1 - m - ls;
    ((float2*)(out + (size_t)node * DIM_OUT))[hl] = o;
  }
}

extern "C" void kernel_launch(void* const* d_in, const int* in_sizes, int n_in,
                              void* d_out, int out_size, void* d_ws, size_t ws_size,
                              hipStream_t stream) {
  const float* x  = (const float*)d_in[0];
  const int*   ei = (const int*)d_in[1];   // [2, E]: first E = dst, next E = src
  const float* ew = (const float*)d_in[2];
  const float* W1 = (const float*)d_in[3];
  const float* W2 = (const float*)d_in[4];
  float* out = (float*)d_out;

  const int* dst = ei;
  const int* src = ei + N_EDGES;

  // ---- workspace: region1 is packed1 during build, h2 (bf16 x64) after ----
  char* p = (char*)d_ws;
  int2*           packed1 = (int2*)p;
  __hip_bfloat16* h2      = (__hip_bfloat16*)p;   // N*64 bf16 = 12.8 MB
  p += (size_t)N_EDGES * 8;                                     // 25.6 MB
  int2* packed2 = (int2*)p;  p += (size_t)(N_EDGES + 16) * 8;   // 25.6 MB + pad
  __hip_bfloat16* h = (__hip_bfloat16*)p;
  p += (size_t)N_NODES * DIM_HID * 2;                           // 12.8 MB
  int* hist   = (int*)p;  p += (size_t)NBUCK * HPAD * 4;        // 100 KB
  int* cursor = (int*)p;  p += (size_t)NBUCK * HPAD * 4;        // 100 KB
  int* base   = (int*)p;  p += (size_t)(NBUCK + 8) * 4;
  int* ptr    = (int*)p;  p += (size_t)(N_NODES + 8) * 4;       // 400 KB

  // ---- build: bucket hist -> scan -> bucket scatter -> in-bucket sort ----
  hipMemsetAsync(hist, 0, (size_t)NBUCK * HPAD * 4, stream);
  hist_kernel<<<NCHUNK, 256, 0, stream>>>(dst, hist);
  scanb_kernel<<<1, 256, 0, stream>>>(hist, base, cursor, ptr);
  scatter_kernel<<<NCHUNK, 256, 0, stream>>>(dst, src, ew, cursor, packed1);
  sort2_kernel<<<NBUCK, 256, 0, stream>>>(base, packed1, packed2, ptr);

  // ---- layer 1 GEMM (bf16 h) ----
  gemm1_kernel<<<N_NODES / 16, 256, 0, stream>>>(x, W1, h);

  // ---- SPMM1 + fused GEMM2 (h2 overwrites packed1; dead by now) ----
  spmm64_g2_kernel<<<N_NODES / 4, 256, 0, stream>>>(ptr, packed2, h, W2, h2);

  // ---- SPMM2 + fused log_softmax ----
  spmm40_lsm_kernel<<<N_NODES / 4, 256, 0, stream>>>(ptr, packed2, h2, out);
}

// Round 9
// 529.055 us; speedup vs baseline: 6.0249x; 1.1781x over previous
//
#include <hip/hip_runtime.h>
#include <hip/hip_bf16.h>
#include <math.h>

#define N_NODES 100000
#define N_EDGES 3200000
#define DIM_IN  128
#define DIM_HID 64
#define DIM_OUT 40

#define SBSHIFT 8
#define SBNODES 256                                  // nodes per super-bucket
#define NSB ((N_NODES + SBNODES - 1) / SBNODES)      // 391
#define HPAD  16                                     // counter stride: 64 B
#define CHUNK 8192
#define NCHUNK ((N_EDGES + CHUNK - 1) / CHUNK)       // 391

// ---- hist: per-WG LDS histogram of dst>>8, flushed to padded global counters
__global__ __launch_bounds__(256) void hist_kernel(
    const int* __restrict__ dst, int* __restrict__ hist) {
  __shared__ int cnt[NSB];
  const int t = threadIdx.x;
  for (int i = t; i < NSB; i += 256) cnt[i] = 0;
  __syncthreads();
  const int e0 = blockIdx.x * CHUNK;
  const int e1 = min(e0 + CHUNK, N_EDGES);
  for (int e = e0 + t; e < e1; e += 256) atomicAdd(&cnt[dst[e] >> SBSHIFT], 1);
  __syncthreads();
  for (int i = t; i < NSB; i += 256) {
    const int c = cnt[i];
    if (c) atomicAdd(&hist[i * HPAD], c);
  }
}

// ---- exclusive scan of 391 super-bucket counts (single block) --------------
__global__ __launch_bounds__(256) void scanb_kernel(
    const int* __restrict__ hist, int* __restrict__ base,
    int* __restrict__ cursor, int* __restrict__ ptr) {
  const int t = threadIdx.x;
  const int i0 = 2 * t, i1 = 2 * t + 1;
  const int v0 = (i0 < NSB) ? hist[i0 * HPAD] : 0;
  const int v1 = (i1 < NSB) ? hist[i1 * HPAD] : 0;
  const int s = v0 + v1;
  const int lane = t & 63, wid = t >> 6;
  int incl = s;
#pragma unroll
  for (int off = 1; off < 64; off <<= 1) {
    int n = __shfl_up(incl, off);
    if (lane >= off) incl += n;
  }
  __shared__ int wsum[4];
  if (lane == 63) wsum[wid] = incl;
  __syncthreads();
  int woff = 0;
  for (int k = 0; k < wid; ++k) woff += wsum[k];
  int run = woff + incl - s;
  if (i0 < NSB) { base[i0] = run; cursor[i0 * HPAD] = run; }
  run += v0;
  if (i1 < NSB) { base[i1] = run; cursor[i1 * HPAD] = run; }
  if (t == 255) { base[NSB] = N_EDGES; ptr[N_NODES] = N_EDGES; }
}

// ---- scatter pass 1: edges -> super-bucket regions, per-WG LDS reservation -
// ~21 edges (~168 B) contiguous per (WG, sb) reservation -> ~1.3x write amp.
__global__ __launch_bounds__(256) void scatter_kernel(
    const int* __restrict__ dst, const int* __restrict__ src,
    const float* __restrict__ ew, int* __restrict__ cursor,
    int2* __restrict__ packed1) {
  __shared__ int cnt[NSB];
  const int t = threadIdx.x;
  for (int i = t; i < NSB; i += 256) cnt[i] = 0;
  __syncthreads();
  const int e0 = blockIdx.x * CHUNK;
  const int e1 = min(e0 + CHUNK, N_EDGES);
  for (int e = e0 + t; e < e1; e += 256) atomicAdd(&cnt[dst[e] >> SBSHIFT], 1);
  __syncthreads();
  for (int i = t; i < NSB; i += 256) {
    const int c = cnt[i];
    cnt[i] = c ? atomicAdd(&cursor[i * HPAD], c) : 0;  // cnt becomes cursor
  }
  __syncthreads();
  for (int e = e0 + t; e < e1; e += 256) {
    const int d = dst[e];
    const int pos = atomicAdd(&cnt[d >> SBSHIFT], 1);
    int2 q;
    q.x = ((d & (SBNODES - 1)) << 20) | src[e];   // src < 2^20, dstLow8 @20
    q.y = __float_as_int(ew[e]);
    packed1[pos] = q;
  }
}

// ---- pass 2: sort each super-bucket to node order; emit ptr ---------------
// One WG per super-bucket (391). Region ~64 KB: reads sequential, writes
// random-within-region (L2-resident, full lines eventually) -> ~1x write amp.
__global__ __launch_bounds__(256) void sortsb_kernel(
    const int* __restrict__ base, const int2* __restrict__ packed1,
    int2* __restrict__ packed2, int* __restrict__ ptr) {
  __shared__ int cnt[SBNODES];
  __shared__ int cur[SBNODES];
  __shared__ int wsum[4];
  const int t = threadIdx.x;
  const int b = blockIdx.x;
  cnt[t] = 0;
  const int e0 = base[b], e1 = base[b + 1];
  __syncthreads();
  for (int e = e0 + t; e < e1; e += 256)
    atomicAdd(&cnt[(packed1[e].x >> 20) & (SBNODES - 1)], 1);
  __syncthreads();
  const int lane = t & 63, wid = t >> 6;
  const int v = cnt[t];
  int incl = v;
#pragma unroll
  for (int off = 1; off < 64; off <<= 1) {
    int n = __shfl_up(incl, off);
    if (lane >= off) incl += n;
  }
  if (lane == 63) wsum[wid] = incl;
  __syncthreads();
  int woff = 0;
  for (int k = 0; k < wid; ++k) woff += wsum[k];
  const int start = e0 + woff + incl - v;
  cur[t] = start;
  const int node = (b << SBSHIFT) + t;
  if (node < N_NODES) ptr[node] = start;
  __syncthreads();
  for (int e = e0 + t; e < e1; e += 256) {
    const int2 p = packed1[e];
    const int pos = atomicAdd(&cur[(p.x >> 20) & (SBNODES - 1)], 1);
    int2 q; q.x = p.x & 0xFFFFF; q.y = p.y;
    packed2[pos] = q;
  }
}

// ---- GEMM1: h = x @ W1 (bf16 out), 16 rows/block -------------------------
__global__ __launch_bounds__(256) void gemm1_kernel(
    const float* __restrict__ x, const float* __restrict__ W1,
    __hip_bfloat16* __restrict__ h) {
  __shared__ float w[DIM_IN * DIM_HID];   // 32 KB
  for (int i = threadIdx.x; i < DIM_IN * DIM_HID; i += 256) w[i] = W1[i];
  __syncthreads();
  const int lane = threadIdx.x & 63, wid = threadIdx.x >> 6;
#pragma unroll
  for (int r = 0; r < 4; ++r) {
    const int row = blockIdx.x * 16 + r * 4 + wid;   // 100000 % 16 == 0
    const float4* xr = (const float4*)(x + (size_t)row * DIM_IN);
    float acc = 0.f;
#pragma unroll 8
    for (int k4 = 0; k4 < DIM_IN / 4; ++k4) {
      const float4 xv = xr[k4];
      acc = fmaf(xv.x, w[(k4 * 4 + 0) * DIM_HID + lane], acc);
      acc = fmaf(xv.y, w[(k4 * 4 + 1) * DIM_HID + lane], acc);
      acc = fmaf(xv.z, w[(k4 * 4 + 2) * DIM_HID + lane], acc);
      acc = fmaf(xv.w, w[(k4 * 4 + 3) * DIM_HID + lane], acc);
    }
    h[(size_t)row * DIM_HID + lane] = __float2bfloat16(acc);
  }
}

__device__ inline float bf_lo(unsigned int g) {
  return __uint_as_float(g << 16);
}
__device__ inline float bf_hi(unsigned int g) {
  return __uint_as_float(g & 0xFFFF0000u);
}

// ---- SPMM1: clean 16-edge main loop + one predicated tail block ------------
__global__ __launch_bounds__(256) void spmm64_g2_kernel(
    const int* __restrict__ ptr, const int2* __restrict__ packed,
    const __hip_bfloat16* __restrict__ hbf, const float* __restrict__ W2,
    __hip_bfloat16* __restrict__ h2) {   // h2 padded to width 64
  __shared__ float w2[DIM_HID * DIM_OUT];   // 10 KB
  for (int i = threadIdx.x; i < DIM_HID * DIM_OUT; i += 256) w2[i] = W2[i];
  __syncthreads();
  const char* __restrict__ hb = (const char*)hbf;
  const int wv = __builtin_amdgcn_readfirstlane(threadIdx.x) >> 6;  // scalar
  const int node = blockIdx.x * 4 + wv;                 // 25000*4 == N
  const int lane = threadIdx.x & 63;
  const int half = lane >> 5, hl = lane & 31;
  const unsigned int voff = (unsigned int)hl * 4u;      // byte offset in row
  const int eb = ptr[node];
  const int ee = ptr[node + 1];
  float acc0 = 0.f, acc1 = 0.f;
  int e = eb;
  for (; e + 16 <= ee; e += 16) {      // clean main loop: no predication
#pragma unroll
    for (int j = 0; j < 8; ++j) {
      const int4 q = *(const int4*)(packed + e + 2 * j);  // wave-uniform
      const int sa = half ? q.z : q.x;
      const float wgt = __int_as_float(half ? q.w : q.y);
      const unsigned int g =
          *(const unsigned int*)(hb + (((unsigned int)sa << 7) + voff));
      acc0 = fmaf(wgt, bf_lo(g), acc0);
      acc1 = fmaf(wgt, bf_hi(g), acc1);
    }
  }
  if (e < ee) {                        // single predicated tail block
#pragma unroll
    for (int j = 0; j < 8; ++j) {
      const int4 q = *(const int4*)(packed + e + 2 * j);  // padded array
      const bool val = (e + 2 * j + half) < ee;
      const int sa = val ? (half ? q.z : q.x) : 0;
      const float wgt = val ? __int_as_float(half ? q.w : q.y) : 0.f;
      const unsigned int g =
          *(const unsigned int*)(hb + (((unsigned int)sa << 7) + voff));
      acc0 = fmaf(wgt, bf_lo(g), acc0);
      acc1 = fmaf(wgt, bf_hi(g), acc1);
    }
  }
  // merge halves: lane hl now holds full dims (2hl, 2hl+1)
  acc0 += __shfl_xor(acc0, 32);
  acc1 += __shfl_xor(acc1, 32);
  // fused GEMM2: s[c] = sum_k relu(agg[k]) * W2[k][c]
  const int c = (lane < DIM_OUT) ? lane : (DIM_OUT - 1);
  float s = 0.f;
#pragma unroll
  for (int k = 0; k < DIM_HID; k += 2) {
    const float v0 = fmaxf(__shfl(acc0, k >> 1), 0.f);
    const float v1 = fmaxf(__shfl(acc1, k >> 1), 0.f);
    s = fmaf(v0, w2[k * DIM_OUT + c], s);
    s = fmaf(v1, w2[(k + 1) * DIM_OUT + c], s);
  }
  // write padded row: dims 0..39 = s, dims 40..63 = 0
  h2[(size_t)node * 64 + lane] =
      __float2bfloat16((lane < DIM_OUT) ? s : 0.f);
}

// ---- SPMM2 (h2 padded to 64) same structure + fused log_softmax ------------
__global__ __launch_bounds__(256) void spmm40_lsm_kernel(
    const int* __restrict__ ptr, const int2* __restrict__ packed,
    const __hip_bfloat16* __restrict__ h2bf, float* __restrict__ out) {
  const char* __restrict__ hb = (const char*)h2bf;
  const int wv = __builtin_amdgcn_readfirstlane(threadIdx.x) >> 6;  // scalar
  const int node = blockIdx.x * 4 + wv;
  const int lane = threadIdx.x & 63;
  const int half = lane >> 5, hl = lane & 31;
  const unsigned int voff = (unsigned int)hl * 4u;
  const int eb = ptr[node];
  const int ee = ptr[node + 1];
  float acc0 = 0.f, acc1 = 0.f;
  int e = eb;
  for (; e + 16 <= ee; e += 16) {
#pragma unroll
    for (int j = 0; j < 8; ++j) {
      const int4 q = *(const int4*)(packed + e + 2 * j);
      const int sa = half ? q.z : q.x;
      const float wgt = __int_as_float(half ? q.w : q.y);
      const unsigned int g =
          *(const unsigned int*)(hb + (((unsigned int)sa << 7) + voff));
      acc0 = fmaf(wgt, bf_lo(g), acc0);
      acc1 = fmaf(wgt, bf_hi(g), acc1);
    }
  }
  if (e < ee) {
#pragma unroll
    for (int j = 0; j < 8; ++j) {
      const int4 q = *(const int4*)(packed + e + 2 * j);
      const bool val = (e + 2 * j + half) < ee;
      const int sa = val ? (half ? q.z : q.x) : 0;
      const float wgt = val ? __int_as_float(half ? q.w : q.y) : 0.f;
      const unsigned int g =
          *(const unsigned int*)(hb + (((unsigned int)sa << 7) + voff));
      acc0 = fmaf(wgt, bf_lo(g), acc0);
      acc1 = fmaf(wgt, bf_hi(g), acc1);
    }
  }
  acc0 += __shfl_xor(acc0, 32);
  acc1 += __shfl_xor(acc1, 32);
  // lane holds dims (2hl, 2hl+1); valid iff hl < 20 (dims < 40)
  const bool val = (hl < DIM_OUT / 2);
  float m = val ? fmaxf(acc0, acc1) : -INFINITY;
#pragma unroll
  for (int off = 16; off > 0; off >>= 1) m = fmaxf(m, __shfl_xor(m, off));
  const float ex = val ? (expf(acc0 - m) + expf(acc1 - m)) : 0.f;
  float s = ex;
#pragma unroll
  for (int off = 16; off > 0; off >>= 1) s += __shfl_xor(s, off);
  const float ls = logf(s);
  if (lane < DIM_OUT / 2) {
    float2 o;
    o.x = acc0 - m - ls;
    o.y = acc1 - m - ls;
    ((float2*)(out + (size_t)node * DIM_OUT))[hl] = o;
  }
}

extern "C" void kernel_launch(void* const* d_in, const int* in_sizes, int n_in,
                              void* d_out, int out_size, void* d_ws, size_t ws_size,
                              hipStream_t stream) {
  const float* x  = (const float*)d_in[0];
  const int*   ei = (const int*)d_in[1];   // [2, E]: first E = dst, next E = src
  const float* ew = (const float*)d_in[2];
  const float* W1 = (const float*)d_in[3];
  const float* W2 = (const float*)d_in[4];
  float* out = (float*)d_out;

  const int* dst = ei;
  const int* src = ei + N_EDGES;

  // ---- workspace: region1 is packed1 during build, h2 (bf16 x64) after ----
  char* p = (char*)d_ws;
  int2*           packed1 = (int2*)p;
  __hip_bfloat16* h2      = (__hip_bfloat16*)p;   // N*64 bf16 = 12.8 MB
  p += (size_t)N_EDGES * 8;                                     // 25.6 MB
  int2* packed2 = (int2*)p;  p += (size_t)(N_EDGES + 16) * 8;   // 25.6 MB + pad
  __hip_bfloat16* h = (__hip_bfloat16*)p;
  p += (size_t)N_NODES * DIM_HID * 2;                           // 12.8 MB
  int* hist   = (int*)p;  p += (size_t)NSB * HPAD * 4;          // 25 KB
  int* cursor = (int*)p;  p += (size_t)NSB * HPAD * 4;          // 25 KB
  int* base   = (int*)p;  p += (size_t)(NSB + 8) * 4;
  int* ptr    = (int*)p;  p += (size_t)(N_NODES + 8) * 4;       // 400 KB

  // ---- build: sb hist -> scan -> sb scatter -> in-sb node sort ----
  hipMemsetAsync(hist, 0, (size_t)NSB * HPAD * 4, stream);
  hist_kernel<<<NCHUNK, 256, 0, stream>>>(dst, hist);
  scanb_kernel<<<1, 256, 0, stream>>>(hist, base, cursor, ptr);
  scatter_kernel<<<NCHUNK, 256, 0, stream>>>(dst, src, ew, cursor, packed1);
  sortsb_kernel<<<NSB, 256, 0, stream>>>(base, packed1, packed2, ptr);

  // ---- layer 1 GEMM (bf16 h) ----
  gemm1_kernel<<<N_NODES / 16, 256, 0, stream>>>(x, W1, h);

  // ---- SPMM1 + fused GEMM2 (h2 overwrites packed1; dead by now) ----
  spmm64_g2_kernel<<<N_NODES / 4, 256, 0, stream>>>(ptr, packed2, h, W2, h2);

  // ---- SPMM2 + fused log_softmax ----
  spmm40_lsm_kernel<<<N_NODES / 4, 256, 0, stream>>>(ptr, packed2, h2, out);
}